// Round 1
// baseline (1311.216 us; speedup 1.0000x reference)
//
#include <hip/hip_runtime.h>

#define NN 100000
#define NE 1600000
#define DIM0 11
#define H 128
#define NL 4
#define NG 4096
#define EPS 1e-5f

static constexpr int NB1 = (NN + 255) / 256;  // scan blocks = 391

// ---------------- degree / CSR build ----------------

__global__ void k_deg(const int* __restrict__ dst, int* __restrict__ cnt) {
    int e = blockIdx.x * 256 + threadIdx.x;
    if (e < NE) atomicAdd(&cnt[dst[e]], 1);
}

__global__ void k_dis(const int* __restrict__ cnt, float* __restrict__ dis) {
    int n = blockIdx.x * 256 + threadIdx.x;
    if (n < NN) dis[n] = rsqrtf((float)(cnt[n] + 1));  // +1 self-loop, deg>=1
}

__global__ void k_scan1(const int* __restrict__ cnt, int* __restrict__ rp, int* __restrict__ bsum) {
    __shared__ int tmp[256];
    int tid = threadIdx.x;
    int i = blockIdx.x * 256 + tid;
    int v = (i < NN) ? cnt[i] : 0;
    tmp[tid] = v;
    __syncthreads();
    for (int off = 1; off < 256; off <<= 1) {
        int t = (tid >= off) ? tmp[tid - off] : 0;
        __syncthreads();
        tmp[tid] += t;
        __syncthreads();
    }
    if (i < NN) rp[i] = tmp[tid] - v;           // exclusive within block
    if (tid == 255) bsum[blockIdx.x] = tmp[tid]; // block total
}

__global__ void k_scan2(const int* __restrict__ bsum, int* __restrict__ boff) {
    __shared__ int tmp[512];
    int tid = threadIdx.x;
    int v = (tid < NB1) ? bsum[tid] : 0;
    tmp[tid] = v;
    __syncthreads();
    for (int off = 1; off < 512; off <<= 1) {
        int t = (tid >= off) ? tmp[tid - off] : 0;
        __syncthreads();
        tmp[tid] += t;
        __syncthreads();
    }
    if (tid < NB1) boff[tid] = tmp[tid] - v;
}

__global__ void k_scan3(int* __restrict__ rp, const int* __restrict__ boff) {
    int i = blockIdx.x * 256 + threadIdx.x;
    if (i < NN) rp[i] += boff[blockIdx.x];
    if (i == 0) rp[NN] = NE;
}

__global__ void k_fill(const int* __restrict__ src, const int* __restrict__ dst,
                       const int* __restrict__ rp, int* __restrict__ fill, int* __restrict__ col) {
    int e = blockIdx.x * 256 + threadIdx.x;
    if (e < NE) {
        int d = dst[e];
        int pos = rp[d] + atomicAdd(&fill[d], 1);
        col[pos] = src[e];
    }
}

// ---------------- embed: h = relu(x @ W_embed + b) ----------------

__global__ __launch_bounds__(256) void k_embed(const float* __restrict__ x, const float* __restrict__ W,
                                               const float* __restrict__ b, float* __restrict__ h) {
    __shared__ float Ws[DIM0 * H];
    int tid = threadIdx.x;
    for (int i = tid; i < DIM0 * H; i += 256) Ws[i] = W[i];
    __syncthreads();
    int node = blockIdx.x * 2 + (tid >> 7);
    int c = tid & 127;
    if (node < NN) {
        float acc = b[c];
#pragma unroll
        for (int k = 0; k < DIM0; k++) acc += x[node * DIM0 + k] * Ws[k * H + c];
        h[node * H + c] = fmaxf(acc, 0.f);
    }
}

// ---------------- GEMM: m = h @ W (N x 128 @ 128 x 128, fp32) ----------------
// 128 rows/block in LDS (64KB). W streamed from L2 as float4 (64KB total, hot).
// Thread: 16 rows x 4 cols accumulators.

__global__ __launch_bounds__(256) void k_gemm(const float* __restrict__ h, const float* __restrict__ W,
                                              float* __restrict__ m) {
    __shared__ float Hs[128 * H];  // 64 KB
    int tid = threadIdx.x;
    int base = blockIdx.x * 128;

    const float4* h4 = (const float4*)h;
    float4* Hs4 = (float4*)Hs;
    for (int i = tid; i < 128 * H / 4; i += 256) {
        int r = i >> 5;         // /32 float4 per row
        int row = base + r;
        Hs4[i] = (row < NN) ? h4[row * 32 + (i & 31)] : make_float4(0.f, 0.f, 0.f, 0.f);
    }
    __syncthreads();

    int cg = tid & 31;   // cols 4*cg .. 4*cg+3
    int rg = tid >> 5;   // rows rg*16 .. rg*16+15
    float acc[16][4];
#pragma unroll
    for (int r = 0; r < 16; r++)
#pragma unroll
        for (int j = 0; j < 4; j++) acc[r][j] = 0.f;

    const float4* W4 = (const float4*)W;
#pragma unroll 4
    for (int k = 0; k < H; k++) {
        float4 w = W4[k * 32 + cg];
#pragma unroll
        for (int r = 0; r < 16; r++) {
            float hv = Hs[(rg * 16 + r) * H + k];
            acc[r][0] += hv * w.x;
            acc[r][1] += hv * w.y;
            acc[r][2] += hv * w.z;
            acc[r][3] += hv * w.w;
        }
    }

    float4* m4 = (float4*)m;
#pragma unroll
    for (int r = 0; r < 16; r++) {
        int row = base + rg * 16 + r;
        if (row < NN) m4[row * 32 + cg] = make_float4(acc[r][0], acc[r][1], acc[r][2], acc[r][3]);
    }
}

// ---------------- fused aggregate + bias + LN + relu + residual ----------------
// One wave per node; lane holds cols (2l, 2l+1). h updated in place.

__global__ __launch_bounds__(256) void k_agg(const float* __restrict__ m, float* __restrict__ h,
                                             const float* __restrict__ dis, const int* __restrict__ rp,
                                             const int* __restrict__ col, const float* __restrict__ b,
                                             const float* __restrict__ gamma, const float* __restrict__ beta) {
    int tid = threadIdx.x;
    int lane = tid & 63;
    int node = blockIdx.x * 4 + (tid >> 6);
    if (node >= NN) return;

    const float2* m2 = (const float2*)m;
    float2* h2 = (float2*)h;

    float dn = dis[node];
    float2 self = m2[node * 64 + lane];
    float ws = dn * dn;
    float ax = self.x * ws, ay = self.y * ws;

    int e0 = rp[node], e1 = rp[node + 1];
    for (int e = e0; e < e1; e++) {
        int s = col[e];
        float w = dis[s] * dn;
        float2 mv = m2[s * 64 + lane];
        ax += mv.x * w;
        ay += mv.y * w;
    }

    float2 bb = ((const float2*)b)[lane];
    ax += bb.x;
    ay += bb.y;

    float ssum = ax + ay;
#pragma unroll
    for (int off = 32; off > 0; off >>= 1) ssum += __shfl_xor(ssum, off, 64);
    float mu = ssum * (1.f / 128.f);
    float dx = ax - mu, dy = ay - mu;
    float vsum = dx * dx + dy * dy;
#pragma unroll
    for (int off = 32; off > 0; off >>= 1) vsum += __shfl_xor(vsum, off, 64);
    float rs = rsqrtf(vsum * (1.f / 128.f) + EPS);

    float2 gm = ((const float2*)gamma)[lane];
    float2 bt = ((const float2*)beta)[lane];
    float vx = fmaxf(dx * rs * gm.x + bt.x, 0.f);
    float vy = fmaxf(dy * rs * gm.y + bt.y, 0.f);

    float2 res = h2[node * 64 + lane];
    h2[node * 64 + lane] = make_float2(vx + res.x, vy + res.y);
}

// ---------------- pooling: per-graph contiguous ranges (batch sorted) ----------------

__global__ void k_range(const int* __restrict__ batch, int* __restrict__ gstart, int* __restrict__ gend) {
    int n = blockIdx.x * 256 + threadIdx.x;
    if (n < NN) {
        int g = batch[n];
        atomicMin(&gstart[g], n);
        atomicMax(&gend[g], n + 1);
    }
}

__global__ __launch_bounds__(256) void k_pool(const float* __restrict__ h, const int* __restrict__ gstart,
                                              const int* __restrict__ gend, const float* __restrict__ Wout,
                                              const float* __restrict__ bout, float* __restrict__ out) {
    int tid = threadIdx.x;
    int lane = tid & 63;
    int g = blockIdx.x * 4 + (tid >> 6);
    if (g >= NG) return;

    int s = gstart[g], e = gend[g];
    const float2* h2 = (const float2*)h;
    float axx = 0.f, ayy = 0.f;
    if (s < e) {
        for (int n = s; n < e; n++) {
            float2 v = h2[n * 64 + lane];
            axx += v.x;
            ayy += v.y;
        }
        float inv = 1.f / (float)(e - s);
        axx *= inv;
        ayy *= inv;
    }
    float2 w = ((const float2*)Wout)[lane];
    float p = axx * w.x + ayy * w.y;
#pragma unroll
    for (int off = 32; off > 0; off >>= 1) p += __shfl_xor(p, off, 64);
    if (lane == 0) out[g] = p + bout[0];
}

// ---------------- launcher ----------------

extern "C" void kernel_launch(void* const* d_in, const int* in_sizes, int n_in,
                              void* d_out, int out_size, void* d_ws, size_t ws_size,
                              hipStream_t stream) {
    const float* x       = (const float*)d_in[0];
    const int*   edge    = (const int*)d_in[1];
    const int*   batch   = (const int*)d_in[2];
    const float* W_embed = (const float*)d_in[3];
    const float* b_embed = (const float*)d_in[4];
    const float* W_gnn   = (const float*)d_in[5];
    const float* b_gnn   = (const float*)d_in[6];
    const float* gamma   = (const float*)d_in[7];
    const float* beta    = (const float*)d_in[8];
    const float* W_out   = (const float*)d_in[9];
    const float* b_out   = (const float*)d_in[10];
    float* out = (float*)d_out;

    char* ws = (char*)d_ws;
    size_t off = 0;
    auto alloc = [&](size_t bytes) -> char* {
        char* p = ws + off;
        off += (bytes + 255) & ~(size_t)255;
        return p;
    };
    float* h    = (float*)alloc((size_t)NN * H * 4);
    float* m    = (float*)alloc((size_t)NN * H * 4);
    float* dis  = (float*)alloc((size_t)NN * 4);
    int*   rp   = (int*)alloc((size_t)(NN + 1) * 4);
    int*   col  = (int*)alloc((size_t)NE * 4);
    int*   cnt  = (int*)alloc((size_t)NN * 4);
    int*   fill = (int*)alloc((size_t)NN * 4);
    int*   bsum = (int*)alloc(512 * 4);
    int*   boff = (int*)alloc(512 * 4);
    int*   gstart = (int*)alloc((size_t)NG * 4);
    int*   gend   = (int*)alloc((size_t)NG * 4);

    const int* srcp = edge;
    const int* dstp = edge + NE;

    hipMemsetAsync(cnt, 0, (size_t)NN * 4, stream);
    hipMemsetAsync(fill, 0, (size_t)NN * 4, stream);
    hipMemsetAsync(gstart, 0x7f, (size_t)NG * 4, stream);  // large sentinel
    hipMemsetAsync(gend, 0, (size_t)NG * 4, stream);

    k_deg<<<(NE + 255) / 256, 256, 0, stream>>>(dstp, cnt);
    k_dis<<<(NN + 255) / 256, 256, 0, stream>>>(cnt, dis);
    k_scan1<<<NB1, 256, 0, stream>>>(cnt, rp, bsum);
    k_scan2<<<1, 512, 0, stream>>>(bsum, boff);
    k_scan3<<<NB1, 256, 0, stream>>>(rp, boff);
    k_fill<<<(NE + 255) / 256, 256, 0, stream>>>(srcp, dstp, rp, fill, col);

    k_embed<<<NN / 2, 256, 0, stream>>>(x, W_embed, b_embed, h);

    for (int l = 0; l < NL; l++) {
        k_gemm<<<(NN + 127) / 128, 256, 0, stream>>>(h, W_gnn + (size_t)l * H * H, m);
        k_agg<<<(NN + 3) / 4, 256, 0, stream>>>(m, h, dis, rp, col,
                                                b_gnn + l * H, gamma + l * H, beta + l * H);
    }

    k_range<<<(NN + 255) / 256, 256, 0, stream>>>(batch, gstart, gend);
    k_pool<<<NG / 4, 256, 0, stream>>>(h, gstart, gend, W_out, b_out, out);
}

// Round 2
// 1111.234 us; speedup vs baseline: 1.1800x; 1.1800x over previous
//
#include <hip/hip_runtime.h>

#define NN 100000
#define NE 1600000
#define DIM0 11
#define H 128
#define NL 4
#define NG 4096
#define EPS 1e-5f

static constexpr int NB1 = (NN + 255) / 256;  // scan blocks = 391

// ---------------- degree / CSR build ----------------

__global__ void k_deg(const int* __restrict__ dst, int* __restrict__ cnt) {
    int e = blockIdx.x * 256 + threadIdx.x;
    if (e < NE) atomicAdd(&cnt[dst[e]], 1);
}

__global__ void k_dis(const int* __restrict__ cnt, float* __restrict__ dis) {
    int n = blockIdx.x * 256 + threadIdx.x;
    if (n < NN) dis[n] = rsqrtf((float)(cnt[n] + 1));  // +1 self-loop, deg>=1
}

__global__ void k_scan1(const int* __restrict__ cnt, int* __restrict__ rp, int* __restrict__ bsum) {
    __shared__ int tmp[256];
    int tid = threadIdx.x;
    int i = blockIdx.x * 256 + tid;
    int v = (i < NN) ? cnt[i] : 0;
    tmp[tid] = v;
    __syncthreads();
    for (int off = 1; off < 256; off <<= 1) {
        int t = (tid >= off) ? tmp[tid - off] : 0;
        __syncthreads();
        tmp[tid] += t;
        __syncthreads();
    }
    if (i < NN) rp[i] = tmp[tid] - v;           // exclusive within block
    if (tid == 255) bsum[blockIdx.x] = tmp[tid]; // block total
}

__global__ void k_scan2(const int* __restrict__ bsum, int* __restrict__ boff) {
    __shared__ int tmp[512];
    int tid = threadIdx.x;
    int v = (tid < NB1) ? bsum[tid] : 0;
    tmp[tid] = v;
    __syncthreads();
    for (int off = 1; off < 512; off <<= 1) {
        int t = (tid >= off) ? tmp[tid - off] : 0;
        __syncthreads();
        tmp[tid] += t;
        __syncthreads();
    }
    if (tid < NB1) boff[tid] = tmp[tid] - v;
}

__global__ void k_scan3(int* __restrict__ rp, const int* __restrict__ boff) {
    int i = blockIdx.x * 256 + threadIdx.x;
    if (i < NN) rp[i] += boff[blockIdx.x];
    if (i == 0) rp[NN] = NE;
}

__global__ void k_fill(const int* __restrict__ src, const int* __restrict__ dst,
                       const int* __restrict__ rp, int* __restrict__ fill, int* __restrict__ col) {
    int e = blockIdx.x * 256 + threadIdx.x;
    if (e < NE) {
        int d = dst[e];
        int pos = rp[d] + atomicAdd(&fill[d], 1);
        col[pos] = src[e];
    }
}

// ---------------- embed: h = relu(x @ W_embed + b) ----------------

__global__ __launch_bounds__(256) void k_embed(const float* __restrict__ x, const float* __restrict__ W,
                                               const float* __restrict__ b, float* __restrict__ h) {
    __shared__ float Ws[DIM0 * H];
    int tid = threadIdx.x;
    for (int i = tid; i < DIM0 * H; i += 256) Ws[i] = W[i];
    __syncthreads();
    int node = blockIdx.x * 2 + (tid >> 7);
    int c = tid & 127;
    if (node < NN) {
        float acc = b[c];
#pragma unroll
        for (int k = 0; k < DIM0; k++) acc += x[node * DIM0 + k] * Ws[k * H + c];
        h[node * H + c] = fmaxf(acc, 0.f);
    }
}

// ---------------- GEMM: m = h @ W (N x 128 @ 128 x 128, fp32) ----------------

__global__ __launch_bounds__(256) void k_gemm(const float* __restrict__ h, const float* __restrict__ W,
                                              float* __restrict__ m) {
    __shared__ float Hs[128 * H];  // 64 KB
    int tid = threadIdx.x;
    int base = blockIdx.x * 128;

    const float4* h4 = (const float4*)h;
    float4* Hs4 = (float4*)Hs;
    for (int i = tid; i < 128 * H / 4; i += 256) {
        int r = i >> 5;         // /32 float4 per row
        int row = base + r;
        Hs4[i] = (row < NN) ? h4[row * 32 + (i & 31)] : make_float4(0.f, 0.f, 0.f, 0.f);
    }
    __syncthreads();

    int cg = tid & 31;   // cols 4*cg .. 4*cg+3
    int rg = tid >> 5;   // rows rg*16 .. rg*16+15
    float acc[16][4];
#pragma unroll
    for (int r = 0; r < 16; r++)
#pragma unroll
        for (int j = 0; j < 4; j++) acc[r][j] = 0.f;

    const float4* W4 = (const float4*)W;
#pragma unroll 4
    for (int k = 0; k < H; k++) {
        float4 w = W4[k * 32 + cg];
#pragma unroll
        for (int r = 0; r < 16; r++) {
            float hv = Hs[(rg * 16 + r) * H + k];
            acc[r][0] += hv * w.x;
            acc[r][1] += hv * w.y;
            acc[r][2] += hv * w.z;
            acc[r][3] += hv * w.w;
        }
    }

    float4* m4 = (float4*)m;
#pragma unroll
    for (int r = 0; r < 16; r++) {
        int row = base + rg * 16 + r;
        if (row < NN) m4[row * 32 + cg] = make_float4(acc[r][0], acc[r][1], acc[r][2], acc[r][3]);
    }
}

// ---------------- fused aggregate + bias + LN + relu + residual ----------------
// One wave per node; lane holds cols (2l, 2l+1). h updated in place.
// Edge loop unrolled x4 with batched loads for memory-level parallelism:
// the serial col->dis/m dependent chain was the round-1 bottleneck
// (VALUBusy 21%, 34% HBM util = latency-bound).

__global__ __launch_bounds__(256) void k_agg(const float* __restrict__ m, float* __restrict__ h,
                                             const float* __restrict__ dis, const int* __restrict__ rp,
                                             const int* __restrict__ col, const float* __restrict__ b,
                                             const float* __restrict__ gamma, const float* __restrict__ beta) {
    int tid = threadIdx.x;
    int lane = tid & 63;
    int node = blockIdx.x * 4 + (tid >> 6);
    if (node >= NN) return;

    const float2* m2 = (const float2*)m;
    float2* h2 = (float2*)h;

    float dn = dis[node];
    float2 self = m2[node * 64 + lane];
    float ws = dn * dn;
    float ax = self.x * ws, ay = self.y * ws;

    int e0 = rp[node], e1 = rp[node + 1];
    int e = e0;
    for (; e + 4 <= e1; e += 4) {
        int s0 = col[e];
        int s1 = col[e + 1];
        int s2 = col[e + 2];
        int s3 = col[e + 3];
        float w0 = dis[s0];
        float w1 = dis[s1];
        float w2 = dis[s2];
        float w3 = dis[s3];
        float2 v0 = m2[s0 * 64 + lane];
        float2 v1 = m2[s1 * 64 + lane];
        float2 v2 = m2[s2 * 64 + lane];
        float2 v3 = m2[s3 * 64 + lane];
        w0 *= dn; w1 *= dn; w2 *= dn; w3 *= dn;
        ax += v0.x * w0; ay += v0.y * w0;
        ax += v1.x * w1; ay += v1.y * w1;
        ax += v2.x * w2; ay += v2.y * w2;
        ax += v3.x * w3; ay += v3.y * w3;
    }
    for (; e < e1; e++) {
        int s = col[e];
        float w = dis[s] * dn;
        float2 mv = m2[s * 64 + lane];
        ax += mv.x * w;
        ay += mv.y * w;
    }

    float2 bb = ((const float2*)b)[lane];
    ax += bb.x;
    ay += bb.y;

    float ssum = ax + ay;
#pragma unroll
    for (int off = 32; off > 0; off >>= 1) ssum += __shfl_xor(ssum, off, 64);
    float mu = ssum * (1.f / 128.f);
    float dx = ax - mu, dy = ay - mu;
    float vsum = dx * dx + dy * dy;
#pragma unroll
    for (int off = 32; off > 0; off >>= 1) vsum += __shfl_xor(vsum, off, 64);
    float rs = rsqrtf(vsum * (1.f / 128.f) + EPS);

    float2 gm = ((const float2*)gamma)[lane];
    float2 bt = ((const float2*)beta)[lane];
    float vx = fmaxf(dx * rs * gm.x + bt.x, 0.f);
    float vy = fmaxf(dy * rs * gm.y + bt.y, 0.f);

    float2 res = h2[node * 64 + lane];
    h2[node * 64 + lane] = make_float2(vx + res.x, vy + res.y);
}

// ---------------- pooling: per-graph contiguous ranges (batch sorted) ----------------

__global__ void k_range(const int* __restrict__ batch, int* __restrict__ gstart, int* __restrict__ gend) {
    int n = blockIdx.x * 256 + threadIdx.x;
    if (n < NN) {
        int g = batch[n];
        atomicMin(&gstart[g], n);
        atomicMax(&gend[g], n + 1);
    }
}

__global__ __launch_bounds__(256) void k_pool(const float* __restrict__ h, const int* __restrict__ gstart,
                                              const int* __restrict__ gend, const float* __restrict__ Wout,
                                              const float* __restrict__ bout, float* __restrict__ out) {
    int tid = threadIdx.x;
    int lane = tid & 63;
    int g = blockIdx.x * 4 + (tid >> 6);
    if (g >= NG) return;

    int s = gstart[g], e = gend[g];
    const float2* h2 = (const float2*)h;
    float axx = 0.f, ayy = 0.f;
    if (s < e) {
        for (int n = s; n < e; n++) {
            float2 v = h2[n * 64 + lane];
            axx += v.x;
            ayy += v.y;
        }
        float inv = 1.f / (float)(e - s);
        axx *= inv;
        ayy *= inv;
    }
    float2 w = ((const float2*)Wout)[lane];
    float p = axx * w.x + ayy * w.y;
#pragma unroll
    for (int off = 32; off > 0; off >>= 1) p += __shfl_xor(p, off, 64);
    if (lane == 0) out[g] = p + bout[0];
}

// ---------------- launcher ----------------

extern "C" void kernel_launch(void* const* d_in, const int* in_sizes, int n_in,
                              void* d_out, int out_size, void* d_ws, size_t ws_size,
                              hipStream_t stream) {
    const float* x       = (const float*)d_in[0];
    const int*   edge    = (const int*)d_in[1];
    const int*   batch   = (const int*)d_in[2];
    const float* W_embed = (const float*)d_in[3];
    const float* b_embed = (const float*)d_in[4];
    const float* W_gnn   = (const float*)d_in[5];
    const float* b_gnn   = (const float*)d_in[6];
    const float* gamma   = (const float*)d_in[7];
    const float* beta    = (const float*)d_in[8];
    const float* W_out   = (const float*)d_in[9];
    const float* b_out   = (const float*)d_in[10];
    float* out = (float*)d_out;

    char* ws = (char*)d_ws;
    size_t off = 0;
    auto alloc = [&](size_t bytes) -> char* {
        char* p = ws + off;
        off += (bytes + 255) & ~(size_t)255;
        return p;
    };
    float* h    = (float*)alloc((size_t)NN * H * 4);
    float* m    = (float*)alloc((size_t)NN * H * 4);
    float* dis  = (float*)alloc((size_t)NN * 4);
    int*   rp   = (int*)alloc((size_t)(NN + 1) * 4);
    int*   col  = (int*)alloc((size_t)NE * 4);
    int*   cnt  = (int*)alloc((size_t)NN * 4);
    int*   fill = (int*)alloc((size_t)NN * 4);
    int*   bsum = (int*)alloc(512 * 4);
    int*   boff = (int*)alloc(512 * 4);
    int*   gstart = (int*)alloc((size_t)NG * 4);
    int*   gend   = (int*)alloc((size_t)NG * 4);

    const int* srcp = edge;
    const int* dstp = edge + NE;

    hipMemsetAsync(cnt, 0, (size_t)NN * 4, stream);
    hipMemsetAsync(fill, 0, (size_t)NN * 4, stream);
    hipMemsetAsync(gstart, 0x7f, (size_t)NG * 4, stream);  // large sentinel
    hipMemsetAsync(gend, 0, (size_t)NG * 4, stream);

    k_deg<<<(NE + 255) / 256, 256, 0, stream>>>(dstp, cnt);
    k_dis<<<(NN + 255) / 256, 256, 0, stream>>>(cnt, dis);
    k_scan1<<<NB1, 256, 0, stream>>>(cnt, rp, bsum);
    k_scan2<<<1, 512, 0, stream>>>(bsum, boff);
    k_scan3<<<NB1, 256, 0, stream>>>(rp, boff);
    k_fill<<<(NE + 255) / 256, 256, 0, stream>>>(srcp, dstp, rp, fill, col);

    k_embed<<<NN / 2, 256, 0, stream>>>(x, W_embed, b_embed, h);

    for (int l = 0; l < NL; l++) {
        k_gemm<<<(NN + 127) / 128, 256, 0, stream>>>(h, W_gnn + (size_t)l * H * H, m);
        k_agg<<<(NN + 3) / 4, 256, 0, stream>>>(m, h, dis, rp, col,
                                                b_gnn + l * H, gamma + l * H, beta + l * H);
    }

    k_range<<<(NN + 255) / 256, 256, 0, stream>>>(batch, gstart, gend);
    k_pool<<<NG / 4, 256, 0, stream>>>(h, gstart, gend, W_out, b_out, out);
}

// Round 3
// 1098.967 us; speedup vs baseline: 1.1931x; 1.0112x over previous
//
#include <hip/hip_runtime.h>

#define NN 100000
#define NE 1600000
#define DIM0 11
#define H 128
#define NL 4
#define NG 4096
#define EPS 1e-5f

static constexpr int NB1 = (NN + 255) / 256;  // scan blocks = 391

// ---------------- degree / CSR build ----------------

__global__ void k_deg(const int* __restrict__ dst, int* __restrict__ cnt) {
    int e = blockIdx.x * 256 + threadIdx.x;
    if (e < NE) atomicAdd(&cnt[dst[e]], 1);
}

__global__ void k_dis(const int* __restrict__ cnt, float* __restrict__ dis) {
    int n = blockIdx.x * 256 + threadIdx.x;
    if (n < NN) dis[n] = rsqrtf((float)(cnt[n] + 1));  // +1 self-loop, deg>=1
}

__global__ void k_scan1(const int* __restrict__ cnt, int* __restrict__ rp, int* __restrict__ bsum) {
    __shared__ int tmp[256];
    int tid = threadIdx.x;
    int i = blockIdx.x * 256 + tid;
    int v = (i < NN) ? cnt[i] : 0;
    tmp[tid] = v;
    __syncthreads();
    for (int off = 1; off < 256; off <<= 1) {
        int t = (tid >= off) ? tmp[tid - off] : 0;
        __syncthreads();
        tmp[tid] += t;
        __syncthreads();
    }
    if (i < NN) rp[i] = tmp[tid] - v;           // exclusive within block
    if (tid == 255) bsum[blockIdx.x] = tmp[tid]; // block total
}

__global__ void k_scan2(const int* __restrict__ bsum, int* __restrict__ boff) {
    __shared__ int tmp[512];
    int tid = threadIdx.x;
    int v = (tid < NB1) ? bsum[tid] : 0;
    tmp[tid] = v;
    __syncthreads();
    for (int off = 1; off < 512; off <<= 1) {
        int t = (tid >= off) ? tmp[tid - off] : 0;
        __syncthreads();
        tmp[tid] += t;
        __syncthreads();
    }
    if (tid < NB1) boff[tid] = tmp[tid] - v;
}

__global__ void k_scan3(int* __restrict__ rp, const int* __restrict__ boff) {
    int i = blockIdx.x * 256 + threadIdx.x;
    if (i < NN) rp[i] += boff[blockIdx.x];
    if (i == 0) rp[NN] = NE;
}

__global__ void k_fill(const int* __restrict__ src, const int* __restrict__ dst,
                       const int* __restrict__ rp, int* __restrict__ fill, int* __restrict__ col) {
    int e = blockIdx.x * 256 + threadIdx.x;
    if (e < NE) {
        int d = dst[e];
        int pos = rp[d] + atomicAdd(&fill[d], 1);
        col[pos] = src[e];
    }
}

// ---------------- embed: h = relu(x @ W_embed + b) ----------------

__global__ __launch_bounds__(256) void k_embed(const float* __restrict__ x, const float* __restrict__ W,
                                               const float* __restrict__ b, float* __restrict__ h) {
    __shared__ float Ws[DIM0 * H];
    int tid = threadIdx.x;
    for (int i = tid; i < DIM0 * H; i += 256) Ws[i] = W[i];
    __syncthreads();
    int node = blockIdx.x * 2 + (tid >> 7);
    int c = tid & 127;
    if (node < NN) {
        float acc = b[c];
#pragma unroll
        for (int k = 0; k < DIM0; k++) acc += x[node * DIM0 + k] * Ws[k * H + c];
        h[node * H + c] = fmaxf(acc, 0.f);
    }
}

// ---------------- GEMM: m = h @ W (N x 128 @ 128 x 128, fp32) ----------------

__global__ __launch_bounds__(256) void k_gemm(const float* __restrict__ h, const float* __restrict__ W,
                                              float* __restrict__ m) {
    __shared__ float Hs[128 * H];  // 64 KB
    int tid = threadIdx.x;
    int base = blockIdx.x * 128;

    const float4* h4 = (const float4*)h;
    float4* Hs4 = (float4*)Hs;
    for (int i = tid; i < 128 * H / 4; i += 256) {
        int r = i >> 5;         // /32 float4 per row
        int row = base + r;
        Hs4[i] = (row < NN) ? h4[row * 32 + (i & 31)] : make_float4(0.f, 0.f, 0.f, 0.f);
    }
    __syncthreads();

    int cg = tid & 31;   // cols 4*cg .. 4*cg+3
    int rg = tid >> 5;   // rows rg*16 .. rg*16+15
    float acc[16][4];
#pragma unroll
    for (int r = 0; r < 16; r++)
#pragma unroll
        for (int j = 0; j < 4; j++) acc[r][j] = 0.f;

    const float4* W4 = (const float4*)W;
#pragma unroll 4
    for (int k = 0; k < H; k++) {
        float4 w = W4[k * 32 + cg];
#pragma unroll
        for (int r = 0; r < 16; r++) {
            float hv = Hs[(rg * 16 + r) * H + k];
            acc[r][0] += hv * w.x;
            acc[r][1] += hv * w.y;
            acc[r][2] += hv * w.z;
            acc[r][3] += hv * w.w;
        }
    }

    float4* m4 = (float4*)m;
#pragma unroll
    for (int r = 0; r < 16; r++) {
        int row = base + rg * 16 + r;
        if (row < NN) m4[row * 32 + cg] = make_float4(acc[r][0], acc[r][1], acc[r][2], acc[r][3]);
    }
}

// ---------------- fused aggregate + bias + LN + relu + residual ----------------
// One wave per node. Lane layout: half = lane>>5 (edge parity), l5 = lane&31
// (float4 column group) -> one vmem instruction gathers TWO rows at 16B/lane.
// x4 per-thread unroll = 8 edges (4KB) in flight per wave. node made
// wave-uniform via readfirstlane so rp/col/dis go through scalar loads
// (constant cache path, overlaps the vector gather path).

__global__ __launch_bounds__(256) void k_agg(const float* __restrict__ m, float* __restrict__ h,
                                             const float* __restrict__ dis, const int* __restrict__ rp,
                                             const int* __restrict__ col, const float* __restrict__ b,
                                             const float* __restrict__ gamma, const float* __restrict__ beta) {
    int tid = threadIdx.x;
    int lane = tid & 63;
    int half = lane >> 5;   // 0: even edges, 1: odd edges
    int l5 = lane & 31;     // float4 column group: cols 4*l5 .. 4*l5+3
    int node = __builtin_amdgcn_readfirstlane(blockIdx.x * 4 + (tid >> 6));
    if (node >= NN) return;

    const float4* m4 = (const float4*)m;
    float4* h4 = (float4*)h;

    float dn = dis[node];
    float ax = 0.f, ay = 0.f, az = 0.f, aw = 0.f;
    if (half == 0) {  // self-loop counted once
        float4 self = m4[(size_t)node * 32 + l5];
        float ws = dn * dn;
        ax = self.x * ws; ay = self.y * ws; az = self.z * ws; aw = self.w * ws;
    }

    int e0 = rp[node], e1 = rp[node + 1];
    int e = e0 + half;
    // thread handles e, e+2, e+4, e+6 (its parity class), 4 at a time
    for (; e + 6 < e1; e += 8) {
        int s0 = col[e];
        int s1 = col[e + 2];
        int s2 = col[e + 4];
        int s3 = col[e + 6];
        float w0 = dis[s0];
        float w1 = dis[s1];
        float w2 = dis[s2];
        float w3 = dis[s3];
        float4 v0 = m4[(size_t)s0 * 32 + l5];
        float4 v1 = m4[(size_t)s1 * 32 + l5];
        float4 v2 = m4[(size_t)s2 * 32 + l5];
        float4 v3 = m4[(size_t)s3 * 32 + l5];
        w0 *= dn; w1 *= dn; w2 *= dn; w3 *= dn;
        ax += v0.x * w0; ay += v0.y * w0; az += v0.z * w0; aw += v0.w * w0;
        ax += v1.x * w1; ay += v1.y * w1; az += v1.z * w1; aw += v1.w * w1;
        ax += v2.x * w2; ay += v2.y * w2; az += v2.z * w2; aw += v2.w * w2;
        ax += v3.x * w3; ay += v3.y * w3; az += v3.z * w3; aw += v3.w * w3;
    }
    for (; e < e1; e += 2) {
        int s = col[e];
        float w = dis[s] * dn;
        float4 v = m4[(size_t)s * 32 + l5];
        ax += v.x * w; ay += v.y * w; az += v.z * w; aw += v.w * w;
    }

    // combine the two edge-parity halves (lane i <-> lane i+32)
    ax += __shfl_xor(ax, 32, 64);
    ay += __shfl_xor(ay, 32, 64);
    az += __shfl_xor(az, 32, 64);
    aw += __shfl_xor(aw, 32, 64);

    float4 bb = ((const float4*)b)[l5];
    ax += bb.x; ay += bb.y; az += bb.z; aw += bb.w;

    // LayerNorm over 128 cols: reduce within the 32-lane half (each col once)
    float ssum = ax + ay + az + aw;
#pragma unroll
    for (int off = 16; off > 0; off >>= 1) ssum += __shfl_xor(ssum, off, 64);
    float mu = ssum * (1.f / 128.f);
    float dx = ax - mu, dy = ay - mu, dz = az - mu, dw = aw - mu;
    float vsum = dx * dx + dy * dy + dz * dz + dw * dw;
#pragma unroll
    for (int off = 16; off > 0; off >>= 1) vsum += __shfl_xor(vsum, off, 64);
    float rs = rsqrtf(vsum * (1.f / 128.f) + EPS);

    if (half == 0) {
        float4 gm = ((const float4*)gamma)[l5];
        float4 bt = ((const float4*)beta)[l5];
        float4 res = h4[(size_t)node * 32 + l5];
        float4 o;
        o.x = fmaxf(dx * rs * gm.x + bt.x, 0.f) + res.x;
        o.y = fmaxf(dy * rs * gm.y + bt.y, 0.f) + res.y;
        o.z = fmaxf(dz * rs * gm.z + bt.z, 0.f) + res.z;
        o.w = fmaxf(dw * rs * gm.w + bt.w, 0.f) + res.w;
        h4[(size_t)node * 32 + l5] = o;
    }
}

// ---------------- pooling: per-graph contiguous ranges (batch sorted) ----------------

__global__ void k_range(const int* __restrict__ batch, int* __restrict__ gstart, int* __restrict__ gend) {
    int n = blockIdx.x * 256 + threadIdx.x;
    if (n < NN) {
        int g = batch[n];
        atomicMin(&gstart[g], n);
        atomicMax(&gend[g], n + 1);
    }
}

__global__ __launch_bounds__(256) void k_pool(const float* __restrict__ h, const int* __restrict__ gstart,
                                              const int* __restrict__ gend, const float* __restrict__ Wout,
                                              const float* __restrict__ bout, float* __restrict__ out) {
    int tid = threadIdx.x;
    int lane = tid & 63;
    int g = blockIdx.x * 4 + (tid >> 6);
    if (g >= NG) return;

    int s = gstart[g], e = gend[g];
    const float2* h2 = (const float2*)h;
    float axx = 0.f, ayy = 0.f;
    if (s < e) {
        for (int n = s; n < e; n++) {
            float2 v = h2[n * 64 + lane];
            axx += v.x;
            ayy += v.y;
        }
        float inv = 1.f / (float)(e - s);
        axx *= inv;
        ayy *= inv;
    }
    float2 w = ((const float2*)Wout)[lane];
    float p = axx * w.x + ayy * w.y;
#pragma unroll
    for (int off = 32; off > 0; off >>= 1) p += __shfl_xor(p, off, 64);
    if (lane == 0) out[g] = p + bout[0];
}

// ---------------- launcher ----------------

extern "C" void kernel_launch(void* const* d_in, const int* in_sizes, int n_in,
                              void* d_out, int out_size, void* d_ws, size_t ws_size,
                              hipStream_t stream) {
    const float* x       = (const float*)d_in[0];
    const int*   edge    = (const int*)d_in[1];
    const int*   batch   = (const int*)d_in[2];
    const float* W_embed = (const float*)d_in[3];
    const float* b_embed = (const float*)d_in[4];
    const float* W_gnn   = (const float*)d_in[5];
    const float* b_gnn   = (const float*)d_in[6];
    const float* gamma   = (const float*)d_in[7];
    const float* beta    = (const float*)d_in[8];
    const float* W_out   = (const float*)d_in[9];
    const float* b_out   = (const float*)d_in[10];
    float* out = (float*)d_out;

    char* ws = (char*)d_ws;
    size_t off = 0;
    auto alloc = [&](size_t bytes) -> char* {
        char* p = ws + off;
        off += (bytes + 255) & ~(size_t)255;
        return p;
    };
    float* h    = (float*)alloc((size_t)NN * H * 4);
    float* m    = (float*)alloc((size_t)NN * H * 4);
    float* dis  = (float*)alloc((size_t)NN * 4);
    int*   rp   = (int*)alloc((size_t)(NN + 1) * 4);
    int*   col  = (int*)alloc((size_t)NE * 4);
    int*   cnt  = (int*)alloc((size_t)NN * 4);
    int*   fill = (int*)alloc((size_t)NN * 4);
    int*   bsum = (int*)alloc(512 * 4);
    int*   boff = (int*)alloc(512 * 4);
    int*   gstart = (int*)alloc((size_t)NG * 4);
    int*   gend   = (int*)alloc((size_t)NG * 4);

    const int* srcp = edge;
    const int* dstp = edge + NE;

    hipMemsetAsync(cnt, 0, (size_t)NN * 4, stream);
    hipMemsetAsync(fill, 0, (size_t)NN * 4, stream);
    hipMemsetAsync(gstart, 0x7f, (size_t)NG * 4, stream);  // large sentinel
    hipMemsetAsync(gend, 0, (size_t)NG * 4, stream);

    k_deg<<<(NE + 255) / 256, 256, 0, stream>>>(dstp, cnt);
    k_dis<<<(NN + 255) / 256, 256, 0, stream>>>(cnt, dis);
    k_scan1<<<NB1, 256, 0, stream>>>(cnt, rp, bsum);
    k_scan2<<<1, 512, 0, stream>>>(bsum, boff);
    k_scan3<<<NB1, 256, 0, stream>>>(rp, boff);
    k_fill<<<(NE + 255) / 256, 256, 0, stream>>>(srcp, dstp, rp, fill, col);

    k_embed<<<NN / 2, 256, 0, stream>>>(x, W_embed, b_embed, h);

    for (int l = 0; l < NL; l++) {
        k_gemm<<<(NN + 127) / 128, 256, 0, stream>>>(h, W_gnn + (size_t)l * H * H, m);
        k_agg<<<(NN + 3) / 4, 256, 0, stream>>>(m, h, dis, rp, col,
                                                b_gnn + l * H, gamma + l * H, beta + l * H);
    }

    k_range<<<(NN + 255) / 256, 256, 0, stream>>>(batch, gstart, gend);
    k_pool<<<NG / 4, 256, 0, stream>>>(h, gstart, gend, W_out, b_out, out);
}

// Round 4
// 899.297 us; speedup vs baseline: 1.4580x; 1.2220x over previous
//
#include <hip/hip_runtime.h>

#define NN 100000
#define NE 1600000
#define DIM0 11
#define H 128
#define NL 4
#define NG 4096
#define EPS 1e-5f

static constexpr int NB1 = (NN + 255) / 256;  // scan blocks = 391

// bf16 helpers: m is stored as bf16 (raw ushort) to halve gather bytes in k_agg,
// which is pinned at the L2-miss/LLC random-gather bandwidth ceiling (r2/r3 evidence).
__device__ __forceinline__ unsigned short f2bf(float f) {
    unsigned int u = __float_as_uint(f);
    unsigned int lsb = (u >> 16) & 1;
    u += 0x7fffu + lsb;             // round-to-nearest-even
    return (unsigned short)(u >> 16);
}
__device__ __forceinline__ float bf2f(unsigned short s) {
    return __uint_as_float((unsigned int)s << 16);
}

// ---------------- degree / CSR build ----------------

__global__ void k_deg(const int* __restrict__ dst, int* __restrict__ cnt) {
    int e = blockIdx.x * 256 + threadIdx.x;
    if (e < NE) atomicAdd(&cnt[dst[e]], 1);
}

__global__ void k_dis(const int* __restrict__ cnt, float* __restrict__ dis) {
    int n = blockIdx.x * 256 + threadIdx.x;
    if (n < NN) dis[n] = rsqrtf((float)(cnt[n] + 1));  // +1 self-loop, deg>=1
}

__global__ void k_scan1(const int* __restrict__ cnt, int* __restrict__ rp, int* __restrict__ bsum) {
    __shared__ int tmp[256];
    int tid = threadIdx.x;
    int i = blockIdx.x * 256 + tid;
    int v = (i < NN) ? cnt[i] : 0;
    tmp[tid] = v;
    __syncthreads();
    for (int off = 1; off < 256; off <<= 1) {
        int t = (tid >= off) ? tmp[tid - off] : 0;
        __syncthreads();
        tmp[tid] += t;
        __syncthreads();
    }
    if (i < NN) rp[i] = tmp[tid] - v;           // exclusive within block
    if (tid == 255) bsum[blockIdx.x] = tmp[tid]; // block total
}

__global__ void k_scan2(const int* __restrict__ bsum, int* __restrict__ boff) {
    __shared__ int tmp[512];
    int tid = threadIdx.x;
    int v = (tid < NB1) ? bsum[tid] : 0;
    tmp[tid] = v;
    __syncthreads();
    for (int off = 1; off < 512; off <<= 1) {
        int t = (tid >= off) ? tmp[tid - off] : 0;
        __syncthreads();
        tmp[tid] += t;
        __syncthreads();
    }
    if (tid < NB1) boff[tid] = tmp[tid] - v;
}

__global__ void k_scan3(int* __restrict__ rp, const int* __restrict__ boff) {
    int i = blockIdx.x * 256 + threadIdx.x;
    if (i < NN) rp[i] += boff[blockIdx.x];
    if (i == 0) rp[NN] = NE;
}

__global__ void k_fill(const int* __restrict__ src, const int* __restrict__ dst,
                       const int* __restrict__ rp, int* __restrict__ fill, int* __restrict__ col) {
    int e = blockIdx.x * 256 + threadIdx.x;
    if (e < NE) {
        int d = dst[e];
        int pos = rp[d] + atomicAdd(&fill[d], 1);
        col[pos] = src[e];
    }
}

// ---------------- embed: h = relu(x @ W_embed + b) ----------------

__global__ __launch_bounds__(256) void k_embed(const float* __restrict__ x, const float* __restrict__ W,
                                               const float* __restrict__ b, float* __restrict__ h) {
    __shared__ float Ws[DIM0 * H];
    int tid = threadIdx.x;
    for (int i = tid; i < DIM0 * H; i += 256) Ws[i] = W[i];
    __syncthreads();
    int node = blockIdx.x * 2 + (tid >> 7);
    int c = tid & 127;
    if (node < NN) {
        float acc = b[c];
#pragma unroll
        for (int k = 0; k < DIM0; k++) acc += x[node * DIM0 + k] * Ws[k * H + c];
        h[node * H + c] = fmaxf(acc, 0.f);
    }
}

// ---------------- GEMM: m = h @ W (N x 128 @ 128 x 128, fp32 math, bf16 out) ----------------

__global__ __launch_bounds__(256) void k_gemm(const float* __restrict__ h, const float* __restrict__ W,
                                              unsigned short* __restrict__ m) {
    __shared__ float Hs[128 * H];  // 64 KB
    int tid = threadIdx.x;
    int base = blockIdx.x * 128;

    const float4* h4 = (const float4*)h;
    float4* Hs4 = (float4*)Hs;
    for (int i = tid; i < 128 * H / 4; i += 256) {
        int r = i >> 5;         // /32 float4 per row
        int row = base + r;
        Hs4[i] = (row < NN) ? h4[row * 32 + (i & 31)] : make_float4(0.f, 0.f, 0.f, 0.f);
    }
    __syncthreads();

    int cg = tid & 31;   // cols 4*cg .. 4*cg+3
    int rg = tid >> 5;   // rows rg*16 .. rg*16+15
    float acc[16][4];
#pragma unroll
    for (int r = 0; r < 16; r++)
#pragma unroll
        for (int j = 0; j < 4; j++) acc[r][j] = 0.f;

    const float4* W4 = (const float4*)W;
#pragma unroll 4
    for (int k = 0; k < H; k++) {
        float4 w = W4[k * 32 + cg];
#pragma unroll
        for (int r = 0; r < 16; r++) {
            float hv = Hs[(rg * 16 + r) * H + k];
            acc[r][0] += hv * w.x;
            acc[r][1] += hv * w.y;
            acc[r][2] += hv * w.z;
            acc[r][3] += hv * w.w;
        }
    }

    ushort4* m4 = (ushort4*)m;
#pragma unroll
    for (int r = 0; r < 16; r++) {
        int row = base + rg * 16 + r;
        if (row < NN)
            m4[(size_t)row * 32 + cg] = make_ushort4(f2bf(acc[r][0]), f2bf(acc[r][1]),
                                                     f2bf(acc[r][2]), f2bf(acc[r][3]));
    }
}

// ---------------- fused aggregate + bias + LN + relu + residual ----------------
// One wave per node. half = lane>>5 (edge parity), l5 = lane&31 (4-col group).
// m rows are bf16 (256 B): ushort4/lane -> one vmem instruction gathers two rows.
// Accumulation/LN in fp32.

__global__ __launch_bounds__(256) void k_agg(const unsigned short* __restrict__ m, float* __restrict__ h,
                                             const float* __restrict__ dis, const int* __restrict__ rp,
                                             const int* __restrict__ col, const float* __restrict__ b,
                                             const float* __restrict__ gamma, const float* __restrict__ beta) {
    int tid = threadIdx.x;
    int lane = tid & 63;
    int half = lane >> 5;   // 0: even edges, 1: odd edges
    int l5 = lane & 31;     // cols 4*l5 .. 4*l5+3
    int node = __builtin_amdgcn_readfirstlane(blockIdx.x * 4 + (tid >> 6));
    if (node >= NN) return;

    const ushort4* m4 = (const ushort4*)m;
    float4* h4 = (float4*)h;

    float dn = dis[node];
    float ax = 0.f, ay = 0.f, az = 0.f, aw = 0.f;
    if (half == 0) {  // self-loop counted once
        ushort4 sv = m4[(size_t)node * 32 + l5];
        float ws = dn * dn;
        ax = bf2f(sv.x) * ws; ay = bf2f(sv.y) * ws;
        az = bf2f(sv.z) * ws; aw = bf2f(sv.w) * ws;
    }

    int e0 = rp[node], e1 = rp[node + 1];
    int e = e0 + half;
    for (; e + 6 < e1; e += 8) {
        int s0 = col[e];
        int s1 = col[e + 2];
        int s2 = col[e + 4];
        int s3 = col[e + 6];
        float w0 = dis[s0];
        float w1 = dis[s1];
        float w2 = dis[s2];
        float w3 = dis[s3];
        ushort4 v0 = m4[(size_t)s0 * 32 + l5];
        ushort4 v1 = m4[(size_t)s1 * 32 + l5];
        ushort4 v2 = m4[(size_t)s2 * 32 + l5];
        ushort4 v3 = m4[(size_t)s3 * 32 + l5];
        w0 *= dn; w1 *= dn; w2 *= dn; w3 *= dn;
        ax += bf2f(v0.x) * w0; ay += bf2f(v0.y) * w0; az += bf2f(v0.z) * w0; aw += bf2f(v0.w) * w0;
        ax += bf2f(v1.x) * w1; ay += bf2f(v1.y) * w1; az += bf2f(v1.z) * w1; aw += bf2f(v1.w) * w1;
        ax += bf2f(v2.x) * w2; ay += bf2f(v2.y) * w2; az += bf2f(v2.z) * w2; aw += bf2f(v2.w) * w2;
        ax += bf2f(v3.x) * w3; ay += bf2f(v3.y) * w3; az += bf2f(v3.z) * w3; aw += bf2f(v3.w) * w3;
    }
    for (; e < e1; e += 2) {
        int s = col[e];
        float w = dis[s] * dn;
        ushort4 v = m4[(size_t)s * 32 + l5];
        ax += bf2f(v.x) * w; ay += bf2f(v.y) * w;
        az += bf2f(v.z) * w; aw += bf2f(v.w) * w;
    }

    // combine the two edge-parity halves (lane i <-> lane i+32)
    ax += __shfl_xor(ax, 32, 64);
    ay += __shfl_xor(ay, 32, 64);
    az += __shfl_xor(az, 32, 64);
    aw += __shfl_xor(aw, 32, 64);

    float4 bb = ((const float4*)b)[l5];
    ax += bb.x; ay += bb.y; az += bb.z; aw += bb.w;

    // LayerNorm over 128 cols: reduce within the 32-lane half (each col once)
    float ssum = ax + ay + az + aw;
#pragma unroll
    for (int off = 16; off > 0; off >>= 1) ssum += __shfl_xor(ssum, off, 64);
    float mu = ssum * (1.f / 128.f);
    float dx = ax - mu, dy = ay - mu, dz = az - mu, dw = aw - mu;
    float vsum = dx * dx + dy * dy + dz * dz + dw * dw;
#pragma unroll
    for (int off = 16; off > 0; off >>= 1) vsum += __shfl_xor(vsum, off, 64);
    float rs = rsqrtf(vsum * (1.f / 128.f) + EPS);

    if (half == 0) {
        float4 gm = ((const float4*)gamma)[l5];
        float4 bt = ((const float4*)beta)[l5];
        float4 res = h4[(size_t)node * 32 + l5];
        float4 o;
        o.x = fmaxf(dx * rs * gm.x + bt.x, 0.f) + res.x;
        o.y = fmaxf(dy * rs * gm.y + bt.y, 0.f) + res.y;
        o.z = fmaxf(dz * rs * gm.z + bt.z, 0.f) + res.z;
        o.w = fmaxf(dw * rs * gm.w + bt.w, 0.f) + res.w;
        h4[(size_t)node * 32 + l5] = o;
    }
}

// ---------------- pooling: per-graph contiguous ranges (batch sorted) ----------------

__global__ void k_range(const int* __restrict__ batch, int* __restrict__ gstart, int* __restrict__ gend) {
    int n = blockIdx.x * 256 + threadIdx.x;
    if (n < NN) {
        int g = batch[n];
        atomicMin(&gstart[g], n);
        atomicMax(&gend[g], n + 1);
    }
}

__global__ __launch_bounds__(256) void k_pool(const float* __restrict__ h, const int* __restrict__ gstart,
                                              const int* __restrict__ gend, const float* __restrict__ Wout,
                                              const float* __restrict__ bout, float* __restrict__ out) {
    int tid = threadIdx.x;
    int lane = tid & 63;
    int g = blockIdx.x * 4 + (tid >> 6);
    if (g >= NG) return;

    int s = gstart[g], e = gend[g];
    const float2* h2 = (const float2*)h;
    float axx = 0.f, ayy = 0.f;
    if (s < e) {
        for (int n = s; n < e; n++) {
            float2 v = h2[n * 64 + lane];
            axx += v.x;
            ayy += v.y;
        }
        float inv = 1.f / (float)(e - s);
        axx *= inv;
        ayy *= inv;
    }
    float2 w = ((const float2*)Wout)[lane];
    float p = axx * w.x + ayy * w.y;
#pragma unroll
    for (int off = 32; off > 0; off >>= 1) p += __shfl_xor(p, off, 64);
    if (lane == 0) out[g] = p + bout[0];
}

// ---------------- launcher ----------------

extern "C" void kernel_launch(void* const* d_in, const int* in_sizes, int n_in,
                              void* d_out, int out_size, void* d_ws, size_t ws_size,
                              hipStream_t stream) {
    const float* x       = (const float*)d_in[0];
    const int*   edge    = (const int*)d_in[1];
    const int*   batch   = (const int*)d_in[2];
    const float* W_embed = (const float*)d_in[3];
    const float* b_embed = (const float*)d_in[4];
    const float* W_gnn   = (const float*)d_in[5];
    const float* b_gnn   = (const float*)d_in[6];
    const float* gamma   = (const float*)d_in[7];
    const float* beta    = (const float*)d_in[8];
    const float* W_out   = (const float*)d_in[9];
    const float* b_out   = (const float*)d_in[10];
    float* out = (float*)d_out;

    char* ws = (char*)d_ws;
    size_t off = 0;
    auto alloc = [&](size_t bytes) -> char* {
        char* p = ws + off;
        off += (bytes + 255) & ~(size_t)255;
        return p;
    };
    float*          h    = (float*)alloc((size_t)NN * H * 4);
    unsigned short* m    = (unsigned short*)alloc((size_t)NN * H * 2);
    float* dis  = (float*)alloc((size_t)NN * 4);
    int*   rp   = (int*)alloc((size_t)(NN + 1) * 4);
    int*   col  = (int*)alloc((size_t)NE * 4);
    int*   cnt  = (int*)alloc((size_t)NN * 4);
    int*   fill = (int*)alloc((size_t)NN * 4);
    int*   bsum = (int*)alloc(512 * 4);
    int*   boff = (int*)alloc(512 * 4);
    int*   gstart = (int*)alloc((size_t)NG * 4);
    int*   gend   = (int*)alloc((size_t)NG * 4);

    const int* srcp = edge;
    const int* dstp = edge + NE;

    hipMemsetAsync(cnt, 0, (size_t)NN * 4, stream);
    hipMemsetAsync(fill, 0, (size_t)NN * 4, stream);
    hipMemsetAsync(gstart, 0x7f, (size_t)NG * 4, stream);  // large sentinel
    hipMemsetAsync(gend, 0, (size_t)NG * 4, stream);

    k_deg<<<(NE + 255) / 256, 256, 0, stream>>>(dstp, cnt);
    k_dis<<<(NN + 255) / 256, 256, 0, stream>>>(cnt, dis);
    k_scan1<<<NB1, 256, 0, stream>>>(cnt, rp, bsum);
    k_scan2<<<1, 512, 0, stream>>>(bsum, boff);
    k_scan3<<<NB1, 256, 0, stream>>>(rp, boff);
    k_fill<<<(NE + 255) / 256, 256, 0, stream>>>(srcp, dstp, rp, fill, col);

    k_embed<<<NN / 2, 256, 0, stream>>>(x, W_embed, b_embed, h);

    for (int l = 0; l < NL; l++) {
        k_gemm<<<(NN + 127) / 128, 256, 0, stream>>>(h, W_gnn + (size_t)l * H * H, m);
        k_agg<<<(NN + 3) / 4, 256, 0, stream>>>(m, h, dis, rp, col,
                                                b_gnn + l * H, gamma + l * H, beta + l * H);
    }

    k_range<<<(NN + 255) / 256, 256, 0, stream>>>(batch, gstart, gend);
    k_pool<<<NG / 4, 256, 0, stream>>>(h, gstart, gend, W_out, b_out, out);
}

// Round 5
// 813.622 us; speedup vs baseline: 1.6116x; 1.1053x over previous
//
#include <hip/hip_runtime.h>

#define NN 100000
#define NE 1600000
#define DIM0 11
#define H 128
#define NL 4
#define NG 4096
#define EPS 1e-5f

#define NBKT 98        // buckets of 1024 nodes: bucket = dst >> 10
#define EPB 4096       // edges per block in phases A/B
static constexpr int NBB = (NE + EPB - 1) / EPB;  // 391

// bf16 helpers: m stored as bf16 to halve gather bytes in k_agg (r4 win).
__device__ __forceinline__ unsigned short f2bf(float f) {
    unsigned int u = __float_as_uint(f);
    unsigned int lsb = (u >> 16) & 1;
    u += 0x7fffu + lsb;             // round-to-nearest-even
    return (unsigned short)(u >> 16);
}
__device__ __forceinline__ float bf2f(unsigned short s) {
    return __uint_as_float((unsigned int)s << 16);
}

// ---------------- bucketed CSR build (no per-node global atomics) ----------------
// r4 evidence: k_fill was 98us with WRITE_SIZE=107MB (partial-line writebacks from
// random 4B stores) + serialized returning atomics on 100K fill counters. The
// bucketed counting sort keeps all per-node work in LDS and makes global writes
// block-contiguous.

__global__ __launch_bounds__(256) void k_bhist(const int* __restrict__ dst, int* __restrict__ bcnt) {
    __shared__ int lc[NBKT];
    int t = threadIdx.x;
    for (int i = t; i < NBKT; i += 256) lc[i] = 0;
    __syncthreads();
    int base = blockIdx.x * EPB;
#pragma unroll
    for (int i = 0; i < 16; i++) {
        int e = base + i * 256 + t;
        if (e < NE) atomicAdd(&lc[dst[e] >> 10], 1);
    }
    __syncthreads();
    for (int i = t; i < NBKT; i += 256)
        if (lc[i]) atomicAdd(&bcnt[i], lc[i]);
}

__global__ void k_bscan(const int* __restrict__ bcnt, int* __restrict__ bbase) {
    __shared__ int tmp[128];
    int t = threadIdx.x;
    int v = (t < NBKT) ? bcnt[t] : 0;
    tmp[t] = v;
    __syncthreads();
    for (int off = 1; off < 128; off <<= 1) {
        int x = (t >= off) ? tmp[t - off] : 0;
        __syncthreads();
        tmp[t] += x;
        __syncthreads();
    }
    if (t < NBKT) bbase[t] = tmp[t] - v;
    if (t == NBKT) bbase[NBKT] = NE;
}

__global__ __launch_bounds__(256) void k_bscatter(const int* __restrict__ src, const int* __restrict__ dst,
                                                  const int* __restrict__ bbase, int* __restrict__ bfill,
                                                  unsigned int* __restrict__ ebuf) {
    __shared__ int lc[NBKT];
    __shared__ int lbase[NBKT];
    int t = threadIdx.x;
    for (int i = t; i < NBKT; i += 256) lc[i] = 0;
    __syncthreads();
    int base = blockIdx.x * EPB;
    int rank[16];
    int bk[16];
    unsigned pk[16];
#pragma unroll
    for (int i = 0; i < 16; i++) {
        int e = base + i * 256 + t;
        if (e < NE) {
            int d = dst[e];
            int s = src[e];
            int b = d >> 10;
            bk[i] = b;
            pk[i] = (unsigned)s | ((unsigned)(d & 1023) << 17);
            rank[i] = atomicAdd(&lc[b], 1);
        } else bk[i] = -1;
    }
    __syncthreads();
    for (int i = t; i < NBKT; i += 256)
        lbase[i] = bbase[i] + (lc[i] ? atomicAdd(&bfill[i], lc[i]) : 0);
    __syncthreads();
#pragma unroll
    for (int i = 0; i < 16; i++) {
        if (bk[i] >= 0)
            ebuf[lbase[bk[i]] + rank[i]] = pk[i];
    }
}

// One block per bucket: local count -> dis, LDS scan -> rp, LDS-atomic scatter -> col.
__global__ __launch_bounds__(256) void k_bcsr(const unsigned int* __restrict__ ebuf,
                                              const int* __restrict__ bbase,
                                              int* __restrict__ rp, int* __restrict__ col,
                                              float* __restrict__ dis) {
    __shared__ int lcnt[1024];
    __shared__ int lfill[1024];
    __shared__ int tsc[256];
    int t = threadIdx.x;
    int b = blockIdx.x;
    int cb = bbase[b];
    int ecnt = bbase[b + 1] - cb;
    int n0 = b << 10;
    int nb = min(1024, NN - n0);

    for (int i = t; i < 1024; i += 256) { lcnt[i] = 0; lfill[i] = 0; }
    __syncthreads();

#pragma unroll 4
    for (int i = t; i < ecnt; i += 256) {
        unsigned p = ebuf[cb + i];
        atomicAdd(&lcnt[p >> 17], 1);
    }
    __syncthreads();

    // dis from degree (+1 self-loop)
    for (int n = t; n < nb; n += 256)
        dis[n0 + n] = rsqrtf((float)(lcnt[n] + 1));

    // exclusive scan of lcnt[0..1023] (4 per thread + Hillis-Steele over 256)
    int v0 = lcnt[4 * t], v1 = lcnt[4 * t + 1], v2 = lcnt[4 * t + 2], v3 = lcnt[4 * t + 3];
    int ts = v0 + v1 + v2 + v3;
    tsc[t] = ts;
    __syncthreads();
    for (int off = 1; off < 256; off <<= 1) {
        int x = (t >= off) ? tsc[t - off] : 0;
        __syncthreads();
        tsc[t] += x;
        __syncthreads();
    }
    int ex = tsc[t] - ts;
    lcnt[4 * t] = ex;
    lcnt[4 * t + 1] = ex + v0;
    lcnt[4 * t + 2] = ex + v0 + v1;
    lcnt[4 * t + 3] = ex + v0 + v1 + v2;
    __syncthreads();

    for (int n = t; n < nb; n += 256)
        rp[n0 + n] = cb + lcnt[n];
    if (b == 0 && t == 0) rp[NN] = NE;

    // scatter col within this bucket's private contiguous region
#pragma unroll 4
    for (int i = t; i < ecnt; i += 256) {
        unsigned p = ebuf[cb + i];
        int dl = p >> 17;
        int s = (int)(p & 0x1FFFFu);
        col[cb + lcnt[dl] + atomicAdd(&lfill[dl], 1)] = s;
    }
}

// ---------------- embed: h = relu(x @ W_embed + b) ----------------

__global__ __launch_bounds__(256) void k_embed(const float* __restrict__ x, const float* __restrict__ W,
                                               const float* __restrict__ b, float* __restrict__ h) {
    __shared__ float Ws[DIM0 * H];
    int tid = threadIdx.x;
    for (int i = tid; i < DIM0 * H; i += 256) Ws[i] = W[i];
    __syncthreads();
    int node = blockIdx.x * 2 + (tid >> 7);
    int c = tid & 127;
    if (node < NN) {
        float acc = b[c];
#pragma unroll
        for (int k = 0; k < DIM0; k++) acc += x[node * DIM0 + k] * Ws[k * H + c];
        h[node * H + c] = fmaxf(acc, 0.f);
    }
}

// ---------------- GEMM: m = h @ W (fp32 math, bf16 out) ----------------

__global__ __launch_bounds__(256) void k_gemm(const float* __restrict__ h, const float* __restrict__ W,
                                              unsigned short* __restrict__ m) {
    __shared__ float Hs[128 * H];  // 64 KB
    int tid = threadIdx.x;
    int base = blockIdx.x * 128;

    const float4* h4 = (const float4*)h;
    float4* Hs4 = (float4*)Hs;
    for (int i = tid; i < 128 * H / 4; i += 256) {
        int r = i >> 5;
        int row = base + r;
        Hs4[i] = (row < NN) ? h4[row * 32 + (i & 31)] : make_float4(0.f, 0.f, 0.f, 0.f);
    }
    __syncthreads();

    int cg = tid & 31;
    int rg = tid >> 5;
    float acc[16][4];
#pragma unroll
    for (int r = 0; r < 16; r++)
#pragma unroll
        for (int j = 0; j < 4; j++) acc[r][j] = 0.f;

    const float4* W4 = (const float4*)W;
#pragma unroll 4
    for (int k = 0; k < H; k++) {
        float4 w = W4[k * 32 + cg];
#pragma unroll
        for (int r = 0; r < 16; r++) {
            float hv = Hs[(rg * 16 + r) * H + k];
            acc[r][0] += hv * w.x;
            acc[r][1] += hv * w.y;
            acc[r][2] += hv * w.z;
            acc[r][3] += hv * w.w;
        }
    }

    ushort4* m4 = (ushort4*)m;
#pragma unroll
    for (int r = 0; r < 16; r++) {
        int row = base + rg * 16 + r;
        if (row < NN)
            m4[(size_t)row * 32 + cg] = make_ushort4(f2bf(acc[r][0]), f2bf(acc[r][1]),
                                                     f2bf(acc[r][2]), f2bf(acc[r][3]));
    }
}

// ---------------- fused aggregate + bias + LN + relu + residual ----------------

__global__ __launch_bounds__(256) void k_agg(const unsigned short* __restrict__ m, float* __restrict__ h,
                                             const float* __restrict__ dis, const int* __restrict__ rp,
                                             const int* __restrict__ col, const float* __restrict__ b,
                                             const float* __restrict__ gamma, const float* __restrict__ beta) {
    int tid = threadIdx.x;
    int lane = tid & 63;
    int half = lane >> 5;
    int l5 = lane & 31;
    int node = __builtin_amdgcn_readfirstlane(blockIdx.x * 4 + (tid >> 6));
    if (node >= NN) return;

    const ushort4* m4 = (const ushort4*)m;
    float4* h4 = (float4*)h;

    float dn = dis[node];
    float ax = 0.f, ay = 0.f, az = 0.f, aw = 0.f;
    if (half == 0) {
        ushort4 sv = m4[(size_t)node * 32 + l5];
        float ws = dn * dn;
        ax = bf2f(sv.x) * ws; ay = bf2f(sv.y) * ws;
        az = bf2f(sv.z) * ws; aw = bf2f(sv.w) * ws;
    }

    int e0 = rp[node], e1 = rp[node + 1];
    int e = e0 + half;
    for (; e + 6 < e1; e += 8) {
        int s0 = col[e];
        int s1 = col[e + 2];
        int s2 = col[e + 4];
        int s3 = col[e + 6];
        float w0 = dis[s0];
        float w1 = dis[s1];
        float w2 = dis[s2];
        float w3 = dis[s3];
        ushort4 v0 = m4[(size_t)s0 * 32 + l5];
        ushort4 v1 = m4[(size_t)s1 * 32 + l5];
        ushort4 v2 = m4[(size_t)s2 * 32 + l5];
        ushort4 v3 = m4[(size_t)s3 * 32 + l5];
        w0 *= dn; w1 *= dn; w2 *= dn; w3 *= dn;
        ax += bf2f(v0.x) * w0; ay += bf2f(v0.y) * w0; az += bf2f(v0.z) * w0; aw += bf2f(v0.w) * w0;
        ax += bf2f(v1.x) * w1; ay += bf2f(v1.y) * w1; az += bf2f(v1.z) * w1; aw += bf2f(v1.w) * w1;
        ax += bf2f(v2.x) * w2; ay += bf2f(v2.y) * w2; az += bf2f(v2.z) * w2; aw += bf2f(v2.w) * w2;
        ax += bf2f(v3.x) * w3; ay += bf2f(v3.y) * w3; az += bf2f(v3.z) * w3; aw += bf2f(v3.w) * w3;
    }
    for (; e < e1; e += 2) {
        int s = col[e];
        float w = dis[s] * dn;
        ushort4 v = m4[(size_t)s * 32 + l5];
        ax += bf2f(v.x) * w; ay += bf2f(v.y) * w;
        az += bf2f(v.z) * w; aw += bf2f(v.w) * w;
    }

    ax += __shfl_xor(ax, 32, 64);
    ay += __shfl_xor(ay, 32, 64);
    az += __shfl_xor(az, 32, 64);
    aw += __shfl_xor(aw, 32, 64);

    float4 bb = ((const float4*)b)[l5];
    ax += bb.x; ay += bb.y; az += bb.z; aw += bb.w;

    float ssum = ax + ay + az + aw;
#pragma unroll
    for (int off = 16; off > 0; off >>= 1) ssum += __shfl_xor(ssum, off, 64);
    float mu = ssum * (1.f / 128.f);
    float dx = ax - mu, dy = ay - mu, dz = az - mu, dw = aw - mu;
    float vsum = dx * dx + dy * dy + dz * dz + dw * dw;
#pragma unroll
    for (int off = 16; off > 0; off >>= 1) vsum += __shfl_xor(vsum, off, 64);
    float rs = rsqrtf(vsum * (1.f / 128.f) + EPS);

    if (half == 0) {
        float4 gm = ((const float4*)gamma)[l5];
        float4 bt = ((const float4*)beta)[l5];
        float4 res = h4[(size_t)node * 32 + l5];
        float4 o;
        o.x = fmaxf(dx * rs * gm.x + bt.x, 0.f) + res.x;
        o.y = fmaxf(dy * rs * gm.y + bt.y, 0.f) + res.y;
        o.z = fmaxf(dz * rs * gm.z + bt.z, 0.f) + res.z;
        o.w = fmaxf(dw * rs * gm.w + bt.w, 0.f) + res.w;
        h4[(size_t)node * 32 + l5] = o;
    }
}

// ---------------- pooling ----------------

__global__ void k_range(const int* __restrict__ batch, int* __restrict__ gstart, int* __restrict__ gend) {
    int n = blockIdx.x * 256 + threadIdx.x;
    if (n < NN) {
        int g = batch[n];
        atomicMin(&gstart[g], n);
        atomicMax(&gend[g], n + 1);
    }
}

__global__ __launch_bounds__(256) void k_pool(const float* __restrict__ h, const int* __restrict__ gstart,
                                              const int* __restrict__ gend, const float* __restrict__ Wout,
                                              const float* __restrict__ bout, float* __restrict__ out) {
    int tid = threadIdx.x;
    int lane = tid & 63;
    int g = blockIdx.x * 4 + (tid >> 6);
    if (g >= NG) return;

    int s = gstart[g], e = gend[g];
    const float2* h2 = (const float2*)h;
    float axx = 0.f, ayy = 0.f;
    if (s < e) {
        for (int n = s; n < e; n++) {
            float2 v = h2[n * 64 + lane];
            axx += v.x;
            ayy += v.y;
        }
        float inv = 1.f / (float)(e - s);
        axx *= inv;
        ayy *= inv;
    }
    float2 w = ((const float2*)Wout)[lane];
    float p = axx * w.x + ayy * w.y;
#pragma unroll
    for (int off = 32; off > 0; off >>= 1) p += __shfl_xor(p, off, 64);
    if (lane == 0) out[g] = p + bout[0];
}

// ---------------- launcher ----------------

extern "C" void kernel_launch(void* const* d_in, const int* in_sizes, int n_in,
                              void* d_out, int out_size, void* d_ws, size_t ws_size,
                              hipStream_t stream) {
    const float* x       = (const float*)d_in[0];
    const int*   edge    = (const int*)d_in[1];
    const int*   batch   = (const int*)d_in[2];
    const float* W_embed = (const float*)d_in[3];
    const float* b_embed = (const float*)d_in[4];
    const float* W_gnn   = (const float*)d_in[5];
    const float* b_gnn   = (const float*)d_in[6];
    const float* gamma   = (const float*)d_in[7];
    const float* beta    = (const float*)d_in[8];
    const float* W_out   = (const float*)d_in[9];
    const float* b_out   = (const float*)d_in[10];
    float* out = (float*)d_out;

    char* ws = (char*)d_ws;
    size_t off = 0;
    auto alloc = [&](size_t bytes) -> char* {
        char* p = ws + off;
        off += (bytes + 255) & ~(size_t)255;
        return p;
    };
    float*          h    = (float*)alloc((size_t)NN * H * 4);
    unsigned short* m    = (unsigned short*)alloc((size_t)NN * H * 2);
    float*        dis  = (float*)alloc((size_t)NN * 4);
    int*          rp   = (int*)alloc((size_t)(NN + 1) * 4);
    int*          col  = (int*)alloc((size_t)NE * 4);
    unsigned int* ebuf = (unsigned int*)alloc((size_t)NE * 4);
    int*          bcnt  = (int*)alloc((NBKT + 1) * 4);
    int*          bbase = (int*)alloc((NBKT + 1) * 4);
    int*          bfill = (int*)alloc((NBKT + 1) * 4);
    int*   gstart = (int*)alloc((size_t)NG * 4);
    int*   gend   = (int*)alloc((size_t)NG * 4);

    const int* srcp = edge;
    const int* dstp = edge + NE;

    hipMemsetAsync(bcnt, 0, (NBKT + 1) * 4, stream);
    hipMemsetAsync(bfill, 0, (NBKT + 1) * 4, stream);
    hipMemsetAsync(gstart, 0x7f, (size_t)NG * 4, stream);
    hipMemsetAsync(gend, 0, (size_t)NG * 4, stream);

    k_bhist<<<NBB, 256, 0, stream>>>(dstp, bcnt);
    k_bscan<<<1, 128, 0, stream>>>(bcnt, bbase);
    k_bscatter<<<NBB, 256, 0, stream>>>(srcp, dstp, bbase, bfill, ebuf);
    k_bcsr<<<NBKT, 256, 0, stream>>>(ebuf, bbase, rp, col, dis);

    k_embed<<<NN / 2, 256, 0, stream>>>(x, W_embed, b_embed, h);

    for (int l = 0; l < NL; l++) {
        k_gemm<<<(NN + 127) / 128, 256, 0, stream>>>(h, W_gnn + (size_t)l * H * H, m);
        k_agg<<<(NN + 3) / 4, 256, 0, stream>>>(m, h, dis, rp, col,
                                                b_gnn + l * H, gamma + l * H, beta + l * H);
    }

    k_range<<<(NN + 255) / 256, 256, 0, stream>>>(batch, gstart, gend);
    k_pool<<<NG / 4, 256, 0, stream>>>(h, gstart, gend, W_out, b_out, out);
}

// Round 6
// 649.910 us; speedup vs baseline: 2.0175x; 1.2519x over previous
//
#include <hip/hip_runtime.h>

#define NN 100000
#define NE 1600000
#define DIM0 11
#define H 128
#define NL 4
#define NG 4096
#define EPS 1e-5f

#define NBKT 98        // buckets of 1024 nodes: bucket = dst >> 10
#define EPB 4096       // edges per block in phases A/B
static constexpr int NBB = (NE + EPB - 1) / EPB;  // 391

typedef short bf16x8 __attribute__((ext_vector_type(8)));
typedef float f32x4 __attribute__((ext_vector_type(4)));
typedef unsigned short usx8 __attribute__((ext_vector_type(8)));

__device__ __forceinline__ unsigned short f2bf(float f) {
    unsigned int u = __float_as_uint(f);
    unsigned int lsb = (u >> 16) & 1;
    u += 0x7fffu + lsb;             // round-to-nearest-even
    return (unsigned short)(u >> 16);
}
__device__ __forceinline__ float bf2f(unsigned short s) {
    return __uint_as_float((unsigned int)s << 16);
}

// ---------------- bucketed CSR build (r5 win: no per-node global atomics) ----------------

__global__ __launch_bounds__(256) void k_bhist(const int* __restrict__ dst, int* __restrict__ bcnt) {
    __shared__ int lc[NBKT];
    int t = threadIdx.x;
    for (int i = t; i < NBKT; i += 256) lc[i] = 0;
    __syncthreads();
    int base = blockIdx.x * EPB;
#pragma unroll
    for (int i = 0; i < 16; i++) {
        int e = base + i * 256 + t;
        if (e < NE) atomicAdd(&lc[dst[e] >> 10], 1);
    }
    __syncthreads();
    for (int i = t; i < NBKT; i += 256)
        if (lc[i]) atomicAdd(&bcnt[i], lc[i]);
}

__global__ void k_bscan(const int* __restrict__ bcnt, int* __restrict__ bbase) {
    __shared__ int tmp[128];
    int t = threadIdx.x;
    int v = (t < NBKT) ? bcnt[t] : 0;
    tmp[t] = v;
    __syncthreads();
    for (int off = 1; off < 128; off <<= 1) {
        int x = (t >= off) ? tmp[t - off] : 0;
        __syncthreads();
        tmp[t] += x;
        __syncthreads();
    }
    if (t < NBKT) bbase[t] = tmp[t] - v;
    if (t == NBKT) bbase[NBKT] = NE;
}

__global__ __launch_bounds__(256) void k_bscatter(const int* __restrict__ src, const int* __restrict__ dst,
                                                  const int* __restrict__ bbase, int* __restrict__ bfill,
                                                  unsigned int* __restrict__ ebuf) {
    __shared__ int lc[NBKT];
    __shared__ int lbase[NBKT];
    int t = threadIdx.x;
    for (int i = t; i < NBKT; i += 256) lc[i] = 0;
    __syncthreads();
    int base = blockIdx.x * EPB;
    int rank[16];
    int bk[16];
    unsigned pk[16];
#pragma unroll
    for (int i = 0; i < 16; i++) {
        int e = base + i * 256 + t;
        if (e < NE) {
            int d = dst[e];
            int s = src[e];
            int b = d >> 10;
            bk[i] = b;
            pk[i] = (unsigned)s | ((unsigned)(d & 1023) << 17);
            rank[i] = atomicAdd(&lc[b], 1);
        } else bk[i] = -1;
    }
    __syncthreads();
    for (int i = t; i < NBKT; i += 256)
        lbase[i] = bbase[i] + (lc[i] ? atomicAdd(&bfill[i], lc[i]) : 0);
    __syncthreads();
#pragma unroll
    for (int i = 0; i < 16; i++) {
        if (bk[i] >= 0)
            ebuf[lbase[bk[i]] + rank[i]] = pk[i];
    }
}

__global__ __launch_bounds__(256) void k_bcsr(const unsigned int* __restrict__ ebuf,
                                              const int* __restrict__ bbase,
                                              int* __restrict__ rp, int* __restrict__ col,
                                              float* __restrict__ dis) {
    __shared__ int lcnt[1024];
    __shared__ int lfill[1024];
    __shared__ int tsc[256];
    int t = threadIdx.x;
    int b = blockIdx.x;
    int cb = bbase[b];
    int ecnt = bbase[b + 1] - cb;
    int n0 = b << 10;
    int nb = min(1024, NN - n0);

    for (int i = t; i < 1024; i += 256) { lcnt[i] = 0; lfill[i] = 0; }
    __syncthreads();

#pragma unroll 4
    for (int i = t; i < ecnt; i += 256) {
        unsigned p = ebuf[cb + i];
        atomicAdd(&lcnt[p >> 17], 1);
    }
    __syncthreads();

    for (int n = t; n < nb; n += 256)
        dis[n0 + n] = rsqrtf((float)(lcnt[n] + 1));

    int v0 = lcnt[4 * t], v1 = lcnt[4 * t + 1], v2 = lcnt[4 * t + 2], v3 = lcnt[4 * t + 3];
    int ts = v0 + v1 + v2 + v3;
    tsc[t] = ts;
    __syncthreads();
    for (int off = 1; off < 256; off <<= 1) {
        int x = (t >= off) ? tsc[t - off] : 0;
        __syncthreads();
        tsc[t] += x;
        __syncthreads();
    }
    int ex = tsc[t] - ts;
    lcnt[4 * t] = ex;
    lcnt[4 * t + 1] = ex + v0;
    lcnt[4 * t + 2] = ex + v0 + v1;
    lcnt[4 * t + 3] = ex + v0 + v1 + v2;
    __syncthreads();

    for (int n = t; n < nb; n += 256)
        rp[n0 + n] = cb + lcnt[n];
    if (b == 0 && t == 0) rp[NN] = NE;

#pragma unroll 4
    for (int i = t; i < ecnt; i += 256) {
        unsigned p = ebuf[cb + i];
        int dl = p >> 17;
        int s = (int)(p & 0x1FFFFu);
        col[cb + lcnt[dl] + atomicAdd(&lfill[dl], 1)] = s;
    }
}

// ---------------- embed: h = relu(x @ W_embed + b); also bf16 copy hb ----------------

__global__ __launch_bounds__(256) void k_embed(const float* __restrict__ x, const float* __restrict__ W,
                                               const float* __restrict__ b, float* __restrict__ h,
                                               unsigned short* __restrict__ hb) {
    __shared__ float Ws[DIM0 * H];
    int tid = threadIdx.x;
    for (int i = tid; i < DIM0 * H; i += 256) Ws[i] = W[i];
    __syncthreads();
    int node = blockIdx.x * 2 + (tid >> 7);
    int c = tid & 127;
    if (node < NN) {
        float acc = b[c];
#pragma unroll
        for (int k = 0; k < DIM0; k++) acc += x[node * DIM0 + k] * Ws[k * H + c];
        float v = fmaxf(acc, 0.f);
        h[node * H + c] = v;
        hb[node * H + c] = f2bf(v);
    }
}

// ---------------- W pack: W[l][k][n] fp32 -> B-fragment-layout bf16 ----------------
// Wp[((l*4+ks)*8+nt)*512 + lane*8 + j] = bf16(W[l][ks*32+(lane>>4)*8+j][nt*16+(lane&15)])

__global__ __launch_bounds__(256) void k_wpack(const float* __restrict__ W, unsigned short* __restrict__ Wp) {
    int t = blockIdx.x * 256 + threadIdx.x;   // 8192 threads
    int lane = t & 63;
    int idx = t >> 6;          // 0..127
    int nt = idx & 7;
    int ks = (idx >> 3) & 3;
    int l = idx >> 5;
    int q = lane >> 4, l15 = lane & 15;
    const float* Wl = W + (size_t)l * H * H;
    unsigned short* o = Wp + (size_t)idx * 512 + lane * 8;
#pragma unroll
    for (int j = 0; j < 8; j++)
        o[j] = f2bf(Wl[(ks * 32 + q * 8 + j) * H + nt * 16 + l15]);
}

// ---------------- GEMM: m = hb @ W (bf16 MFMA, fp32 accum, bf16 out) ----------------
// Block = 4 waves x 16 rows = 64 rows. Wave computes 16x128 via 8 col-tiles x 4 k-steps
// of mfma_f32_16x16x32_bf16. Verified layouts: A[m=lane&15][k=(lane>>4)*8+j],
// B[n=lane&15][k=(lane>>4)*8+j], C row=(lane>>4)*4+reg, col=lane&15.

__global__ __launch_bounds__(256) void k_gemm(const unsigned short* __restrict__ hb,
                                              const unsigned short* __restrict__ Wp,
                                              unsigned short* __restrict__ m) {
    __shared__ unsigned short Ls[4][16][136];  // stride 136: 16B-aligned rows, bank-spread
    int tid = threadIdx.x;
    int wave = tid >> 6;
    int lane = tid & 63;
    int q = lane >> 4, l15 = lane & 15;
    int rbase = blockIdx.x * 64 + wave * 16;

    // A fragments: 4 k-steps, each lane 8 consecutive bf16 along k
    const bf16x8* hb8 = (const bf16x8*)hb;
    int arow = rbase + l15;
    if (arow >= NN) arow = NN - 1;      // clamp; polluted C rows are store-guarded
    bf16x8 a[4];
#pragma unroll
    for (int ks = 0; ks < 4; ks++)
        a[ks] = hb8[(size_t)arow * 16 + ks * 4 + q];

    const bf16x8* wp8 = (const bf16x8*)Wp;
#pragma unroll
    for (int nt = 0; nt < 8; nt++) {
        f32x4 acc = {0.f, 0.f, 0.f, 0.f};
#pragma unroll
        for (int ks = 0; ks < 4; ks++) {
            bf16x8 bf = wp8[(ks * 8 + nt) * 64 + lane];
            acc = __builtin_amdgcn_mfma_f32_16x16x32_bf16(a[ks], bf, acc, 0, 0, 0);
        }
#pragma unroll
        for (int r = 0; r < 4; r++)
            Ls[wave][q * 4 + r][nt * 16 + l15] = f2bf(acc[r]);
    }

    // wave-private epilogue copy: 16 rows x 128 cols bf16, coalesced 16B chunks
    usx8* m8 = (usx8*)m;
#pragma unroll
    for (int it = 0; it < 4; it++) {
        int c = it * 64 + lane;
        int rr = c >> 4, ck = c & 15;
        int row = rbase + rr;
        if (row < NN) {
            usx8 v = *(const usx8*)&Ls[wave][rr][ck * 8];
            m8[(size_t)row * 16 + ck] = v;
        }
    }
}

// ---------------- fused aggregate + bias + LN + relu + residual ----------------
// r5 evidence: 256B-row gathers at 8B/lane dropped fetch BW to 2.5 TB/s (latency-
// bound). New layout: q=lane>>4 picks edge, l4=lane&15 picks 8-col group ->
// ushort8 (16B/lane) gathers = 4 rows (1KB) per vmem instruction; unroll 4 ->
// 16 edges (4KB) in flight per wave. Also emits hb (bf16 h) for the MFMA GEMM.

__global__ __launch_bounds__(256) void k_agg(const unsigned short* __restrict__ m, float* __restrict__ h,
                                             unsigned short* __restrict__ hb,
                                             const float* __restrict__ dis, const int* __restrict__ rp,
                                             const int* __restrict__ col, const float* __restrict__ b,
                                             const float* __restrict__ gamma, const float* __restrict__ beta) {
    int tid = threadIdx.x;
    int lane = tid & 63;
    int q = lane >> 4;      // edge slot within gather group
    int l4 = lane & 15;     // cols 8*l4 .. 8*l4+7
    int node = __builtin_amdgcn_readfirstlane(blockIdx.x * 4 + (tid >> 6));
    if (node >= NN) return;

    const usx8* m8 = (const usx8*)m;
    float4* h4 = (float4*)h;

    float dn = dis[node];
    float a[8];
#pragma unroll
    for (int j = 0; j < 8; j++) a[j] = 0.f;
    if (q == 0) {  // self-loop counted once
        usx8 sv = m8[(size_t)node * 16 + l4];
        float ws = dn * dn;
#pragma unroll
        for (int j = 0; j < 8; j++) a[j] = bf2f(sv[j]) * ws;
    }

    int e0 = rp[node], e1 = rp[node + 1];
    int e = e0 + q;
    for (; e + 12 < e1; e += 16) {
        int s0 = col[e];
        int s1 = col[e + 4];
        int s2 = col[e + 8];
        int s3 = col[e + 12];
        float w0 = dis[s0];
        float w1 = dis[s1];
        float w2 = dis[s2];
        float w3 = dis[s3];
        usx8 v0 = m8[(size_t)s0 * 16 + l4];
        usx8 v1 = m8[(size_t)s1 * 16 + l4];
        usx8 v2 = m8[(size_t)s2 * 16 + l4];
        usx8 v3 = m8[(size_t)s3 * 16 + l4];
        w0 *= dn; w1 *= dn; w2 *= dn; w3 *= dn;
#pragma unroll
        for (int j = 0; j < 8; j++) {
            a[j] += bf2f(v0[j]) * w0;
            a[j] += bf2f(v1[j]) * w1;
            a[j] += bf2f(v2[j]) * w2;
            a[j] += bf2f(v3[j]) * w3;
        }
    }
    for (; e < e1; e += 4) {
        int s = col[e];
        float w = dis[s] * dn;
        usx8 v = m8[(size_t)s * 16 + l4];
#pragma unroll
        for (int j = 0; j < 8; j++) a[j] += bf2f(v[j]) * w;
    }

    // combine the 4 edge-slot quarters (lanes with equal l4 hold same cols)
#pragma unroll
    for (int j = 0; j < 8; j++) {
        a[j] += __shfl_xor(a[j], 16, 64);
        a[j] += __shfl_xor(a[j], 32, 64);
    }

    float4 b0 = ((const float4*)b)[2 * l4];
    float4 b1 = ((const float4*)b)[2 * l4 + 1];
    a[0] += b0.x; a[1] += b0.y; a[2] += b0.z; a[3] += b0.w;
    a[4] += b1.x; a[5] += b1.y; a[6] += b1.z; a[7] += b1.w;

    // LayerNorm over 128 cols (reduce across the 16 l4 groups; quarters identical)
    float ssum = 0.f;
#pragma unroll
    for (int j = 0; j < 8; j++) ssum += a[j];
#pragma unroll
    for (int off = 8; off > 0; off >>= 1) ssum += __shfl_xor(ssum, off, 64);
    float mu = ssum * (1.f / 128.f);
    float d[8];
    float vsum = 0.f;
#pragma unroll
    for (int j = 0; j < 8; j++) { d[j] = a[j] - mu; vsum += d[j] * d[j]; }
#pragma unroll
    for (int off = 8; off > 0; off >>= 1) vsum += __shfl_xor(vsum, off, 64);
    float rs = rsqrtf(vsum * (1.f / 128.f) + EPS);

    if (q == 0) {
        float4 g0 = ((const float4*)gamma)[2 * l4];
        float4 g1 = ((const float4*)gamma)[2 * l4 + 1];
        float4 t0 = ((const float4*)beta)[2 * l4];
        float4 t1 = ((const float4*)beta)[2 * l4 + 1];
        float4 r0 = h4[(size_t)node * 32 + 2 * l4];
        float4 r1 = h4[(size_t)node * 32 + 2 * l4 + 1];
        float o[8];
        o[0] = fmaxf(d[0] * rs * g0.x + t0.x, 0.f) + r0.x;
        o[1] = fmaxf(d[1] * rs * g0.y + t0.y, 0.f) + r0.y;
        o[2] = fmaxf(d[2] * rs * g0.z + t0.z, 0.f) + r0.z;
        o[3] = fmaxf(d[3] * rs * g0.w + t0.w, 0.f) + r0.w;
        o[4] = fmaxf(d[4] * rs * g1.x + t1.x, 0.f) + r1.x;
        o[5] = fmaxf(d[5] * rs * g1.y + t1.y, 0.f) + r1.y;
        o[6] = fmaxf(d[6] * rs * g1.z + t1.z, 0.f) + r1.z;
        o[7] = fmaxf(d[7] * rs * g1.w + t1.w, 0.f) + r1.w;
        h4[(size_t)node * 32 + 2 * l4]     = make_float4(o[0], o[1], o[2], o[3]);
        h4[(size_t)node * 32 + 2 * l4 + 1] = make_float4(o[4], o[5], o[6], o[7]);
        usx8 ob;
#pragma unroll
        for (int j = 0; j < 8; j++) ob[j] = f2bf(o[j]);
        ((usx8*)hb)[(size_t)node * 16 + l4] = ob;
    }
}

// ---------------- pooling ----------------

__global__ void k_range(const int* __restrict__ batch, int* __restrict__ gstart, int* __restrict__ gend) {
    int n = blockIdx.x * 256 + threadIdx.x;
    if (n < NN) {
        int g = batch[n];
        atomicMin(&gstart[g], n);
        atomicMax(&gend[g], n + 1);
    }
}

__global__ __launch_bounds__(256) void k_pool(const float* __restrict__ h, const int* __restrict__ gstart,
                                              const int* __restrict__ gend, const float* __restrict__ Wout,
                                              const float* __restrict__ bout, float* __restrict__ out) {
    int tid = threadIdx.x;
    int lane = tid & 63;
    int g = blockIdx.x * 4 + (tid >> 6);
    if (g >= NG) return;

    int s = gstart[g], e = gend[g];
    const float2* h2 = (const float2*)h;
    float axx = 0.f, ayy = 0.f;
    if (s < e) {
        for (int n = s; n < e; n++) {
            float2 v = h2[n * 64 + lane];
            axx += v.x;
            ayy += v.y;
        }
        float inv = 1.f / (float)(e - s);
        axx *= inv;
        ayy *= inv;
    }
    float2 w = ((const float2*)Wout)[lane];
    float p = axx * w.x + ayy * w.y;
#pragma unroll
    for (int off = 32; off > 0; off >>= 1) p += __shfl_xor(p, off, 64);
    if (lane == 0) out[g] = p + bout[0];
}

// ---------------- launcher ----------------

extern "C" void kernel_launch(void* const* d_in, const int* in_sizes, int n_in,
                              void* d_out, int out_size, void* d_ws, size_t ws_size,
                              hipStream_t stream) {
    const float* x       = (const float*)d_in[0];
    const int*   edge    = (const int*)d_in[1];
    const int*   batch   = (const int*)d_in[2];
    const float* W_embed = (const float*)d_in[3];
    const float* b_embed = (const float*)d_in[4];
    const float* W_gnn   = (const float*)d_in[5];
    const float* b_gnn   = (const float*)d_in[6];
    const float* gamma   = (const float*)d_in[7];
    const float* beta    = (const float*)d_in[8];
    const float* W_out   = (const float*)d_in[9];
    const float* b_out   = (const float*)d_in[10];
    float* out = (float*)d_out;

    char* ws = (char*)d_ws;
    size_t off = 0;
    auto alloc = [&](size_t bytes) -> char* {
        char* p = ws + off;
        off += (bytes + 255) & ~(size_t)255;
        return p;
    };
    float*          h    = (float*)alloc((size_t)NN * H * 4);
    unsigned short* hb   = (unsigned short*)alloc((size_t)NN * H * 2);
    unsigned short* m    = (unsigned short*)alloc((size_t)NN * H * 2);
    unsigned short* Wp   = (unsigned short*)alloc((size_t)NL * 4 * 8 * 512 * 2);
    float*        dis  = (float*)alloc((size_t)NN * 4);
    int*          rp   = (int*)alloc((size_t)(NN + 1) * 4);
    int*          col  = (int*)alloc((size_t)NE * 4);
    unsigned int* ebuf = (unsigned int*)alloc((size_t)NE * 4);
    int*          bcnt  = (int*)alloc((NBKT + 1) * 4);
    int*          bbase = (int*)alloc((NBKT + 1) * 4);
    int*          bfill = (int*)alloc((NBKT + 1) * 4);
    int*   gstart = (int*)alloc((size_t)NG * 4);
    int*   gend   = (int*)alloc((size_t)NG * 4);

    const int* srcp = edge;
    const int* dstp = edge + NE;

    hipMemsetAsync(bcnt, 0, (NBKT + 1) * 4, stream);
    hipMemsetAsync(bfill, 0, (NBKT + 1) * 4, stream);
    hipMemsetAsync(gstart, 0x7f, (size_t)NG * 4, stream);
    hipMemsetAsync(gend, 0, (size_t)NG * 4, stream);

    k_bhist<<<NBB, 256, 0, stream>>>(dstp, bcnt);
    k_bscan<<<1, 128, 0, stream>>>(bcnt, bbase);
    k_bscatter<<<NBB, 256, 0, stream>>>(srcp, dstp, bbase, bfill, ebuf);
    k_bcsr<<<NBKT, 256, 0, stream>>>(ebuf, bbase, rp, col, dis);

    k_wpack<<<32, 256, 0, stream>>>(W_gnn, Wp);
    k_embed<<<NN / 2, 256, 0, stream>>>(x, W_embed, b_embed, h, hb);

    for (int l = 0; l < NL; l++) {
        k_gemm<<<(NN + 63) / 64, 256, 0, stream>>>(hb, Wp + (size_t)l * 4 * 8 * 512, m);
        k_agg<<<(NN + 3) / 4, 256, 0, stream>>>(m, h, hb, dis, rp, col,
                                                b_gnn + l * H, gamma + l * H, beta + l * H);
    }

    k_range<<<(NN + 255) / 256, 256, 0, stream>>>(batch, gstart, gend);
    k_pool<<<NG / 4, 256, 0, stream>>>(h, gstart, gend, W_out, b_out, out);
}

// Round 7
// 586.702 us; speedup vs baseline: 2.2349x; 1.1077x over previous
//
#include <hip/hip_runtime.h>

#define NN 100000
#define NE 1600000
#define DIM0 11
#define H 128
#define NL 4
#define NG 4096
#define EPS 1e-5f

#define NBKT 98        // buckets of 1024 nodes: bucket = dst >> 10
#define EPB 4096       // edges per block in phases A/B
static constexpr int NBB = (NE + EPB - 1) / EPB;  // 391

typedef _Float16 f16x8 __attribute__((ext_vector_type(8)));
typedef _Float16 f16x2 __attribute__((ext_vector_type(2)));
typedef float f32x4 __attribute__((ext_vector_type(4)));

// ---------------- init (replaces 4 memsets) ----------------

__global__ void k_init(int* __restrict__ bcnt, int* __restrict__ bfill,
                       int* __restrict__ gstart, int* __restrict__ gend) {
    int i = blockIdx.x * 256 + threadIdx.x;
    if (i <= NBKT) { bcnt[i] = 0; bfill[i] = 0; }
    if (i < NG) { gstart[i] = 0x7fffffff; gend[i] = 0; }
}

// ---------------- bucketed CSR build (r5 win: no per-node global atomics) ----------------

__global__ __launch_bounds__(256) void k_bhist(const int* __restrict__ dst, int* __restrict__ bcnt) {
    __shared__ int lc[NBKT];
    int t = threadIdx.x;
    for (int i = t; i < NBKT; i += 256) lc[i] = 0;
    __syncthreads();
    int base = blockIdx.x * EPB;
#pragma unroll
    for (int i = 0; i < 16; i++) {
        int e = base + i * 256 + t;
        if (e < NE) atomicAdd(&lc[dst[e] >> 10], 1);
    }
    __syncthreads();
    for (int i = t; i < NBKT; i += 256)
        if (lc[i]) atomicAdd(&bcnt[i], lc[i]);
}

__global__ void k_bscan(const int* __restrict__ bcnt, int* __restrict__ bbase) {
    __shared__ int tmp[128];
    int t = threadIdx.x;
    int v = (t < NBKT) ? bcnt[t] : 0;
    tmp[t] = v;
    __syncthreads();
    for (int off = 1; off < 128; off <<= 1) {
        int x = (t >= off) ? tmp[t - off] : 0;
        __syncthreads();
        tmp[t] += x;
        __syncthreads();
    }
    if (t < NBKT) bbase[t] = tmp[t] - v;
    if (t == NBKT) bbase[NBKT] = NE;
}

__global__ __launch_bounds__(256) void k_bscatter(const int* __restrict__ src, const int* __restrict__ dst,
                                                  const int* __restrict__ bbase, int* __restrict__ bfill,
                                                  unsigned int* __restrict__ ebuf) {
    __shared__ int lc[NBKT];
    __shared__ int lbase[NBKT];
    int t = threadIdx.x;
    for (int i = t; i < NBKT; i += 256) lc[i] = 0;
    __syncthreads();
    int base = blockIdx.x * EPB;
    int rank[16];
    int bk[16];
    unsigned pk[16];
#pragma unroll
    for (int i = 0; i < 16; i++) {
        int e = base + i * 256 + t;
        if (e < NE) {
            int d = dst[e];
            int s = src[e];
            int b = d >> 10;
            bk[i] = b;
            pk[i] = (unsigned)s | ((unsigned)(d & 1023) << 17);
            rank[i] = atomicAdd(&lc[b], 1);
        } else bk[i] = -1;
    }
    __syncthreads();
    for (int i = t; i < NBKT; i += 256)
        lbase[i] = bbase[i] + (lc[i] ? atomicAdd(&bfill[i], lc[i]) : 0);
    __syncthreads();
#pragma unroll
    for (int i = 0; i < 16; i++) {
        if (bk[i] >= 0)
            ebuf[lbase[bk[i]] + rank[i]] = pk[i];
    }
}

__global__ __launch_bounds__(256) void k_bcsr(const unsigned int* __restrict__ ebuf,
                                              const int* __restrict__ bbase,
                                              int* __restrict__ rp, int* __restrict__ col,
                                              float* __restrict__ dis) {
    __shared__ int lcnt[1024];
    __shared__ int lfill[1024];
    __shared__ int tsc[256];
    int t = threadIdx.x;
    int b = blockIdx.x;
    int cb = bbase[b];
    int ecnt = bbase[b + 1] - cb;
    int n0 = b << 10;
    int nb = min(1024, NN - n0);

    for (int i = t; i < 1024; i += 256) { lcnt[i] = 0; lfill[i] = 0; }
    __syncthreads();

#pragma unroll 4
    for (int i = t; i < ecnt; i += 256) {
        unsigned p = ebuf[cb + i];
        atomicAdd(&lcnt[p >> 17], 1);
    }
    __syncthreads();

    for (int n = t; n < nb; n += 256)
        dis[n0 + n] = rsqrtf((float)(lcnt[n] + 1));

    int v0 = lcnt[4 * t], v1 = lcnt[4 * t + 1], v2 = lcnt[4 * t + 2], v3 = lcnt[4 * t + 3];
    int ts = v0 + v1 + v2 + v3;
    tsc[t] = ts;
    __syncthreads();
    for (int off = 1; off < 256; off <<= 1) {
        int x = (t >= off) ? tsc[t - off] : 0;
        __syncthreads();
        tsc[t] += x;
        __syncthreads();
    }
    int ex = tsc[t] - ts;
    lcnt[4 * t] = ex;
    lcnt[4 * t + 1] = ex + v0;
    lcnt[4 * t + 2] = ex + v0 + v1;
    lcnt[4 * t + 3] = ex + v0 + v1 + v2;
    __syncthreads();

    for (int n = t; n < nb; n += 256)
        rp[n0 + n] = cb + lcnt[n];
    if (b == 0 && t == 0) rp[NN] = NE;

#pragma unroll 4
    for (int i = t; i < ecnt; i += 256) {
        unsigned p = ebuf[cb + i];
        int dl = p >> 17;
        int s = (int)(p & 0x1FFFFu);
        col[cb + lcnt[dl] + atomicAdd(&lfill[dl], 1)] = s;
    }
}

// ---------------- embed: hh = fp16(relu(x @ W_embed + b)) ----------------

__global__ __launch_bounds__(256) void k_embed(const float* __restrict__ x, const float* __restrict__ W,
                                               const float* __restrict__ b, _Float16* __restrict__ hh) {
    __shared__ float Ws[DIM0 * H];
    int tid = threadIdx.x;
    for (int i = tid; i < DIM0 * H; i += 256) Ws[i] = W[i];
    __syncthreads();
    int node = blockIdx.x * 2 + (tid >> 7);
    int c = tid & 127;
    if (node < NN) {
        float acc = b[c];
#pragma unroll
        for (int k = 0; k < DIM0; k++) acc += x[node * DIM0 + k] * Ws[k * H + c];
        _Float16 v = (_Float16)fmaxf(acc, 0.f);
        __builtin_nontemporal_store(v, &hh[(size_t)node * H + c]);
    }
}

// ---------------- W pack: W[l][k][n] fp32 -> B-fragment-layout fp16 ----------------
// Wp[((l*4+ks)*8+nt)*512 + lane*8 + j] = fp16(W[l][ks*32+(lane>>4)*8+j][nt*16+(lane&15)])

__global__ __launch_bounds__(256) void k_wpack(const float* __restrict__ W, _Float16* __restrict__ Wp) {
    int t = blockIdx.x * 256 + threadIdx.x;   // 8192 threads
    int lane = t & 63;
    int idx = t >> 6;          // 0..127
    int nt = idx & 7;
    int ks = (idx >> 3) & 3;
    int l = idx >> 5;
    int q = lane >> 4, l15 = lane & 15;
    const float* Wl = W + (size_t)l * H * H;
    _Float16* o = Wp + (size_t)idx * 512 + lane * 8;
#pragma unroll
    for (int j = 0; j < 8; j++)
        o[j] = (_Float16)(Wl[(ks * 32 + q * 8 + j) * H + nt * 16 + l15]);
}

// ---------------- GEMM: m = hh @ W (fp16 MFMA, fp32 accum, fp16 out) ----------------
// Block = 4 waves x 16 rows. Wave computes 16x128 via 8 col-tiles x 4 k-steps of
// mfma_f32_16x16x32_f16. A[m=lane&15][k=(lane>>4)*8+j], B[n=lane&15][k=same],
// C row=(lane>>4)*4+reg, col=lane&15 (dtype-independent layouts).

__global__ __launch_bounds__(256) void k_gemm(const _Float16* __restrict__ hh,
                                              const _Float16* __restrict__ Wp,
                                              _Float16* __restrict__ m) {
    __shared__ _Float16 Ls[4][16][136];  // row stride 272B (16B-aligned), bank-spread
    int tid = threadIdx.x;
    int wave = tid >> 6;
    int lane = tid & 63;
    int q = lane >> 4, l15 = lane & 15;
    int rbase = blockIdx.x * 64 + wave * 16;

    const f16x8* hh8 = (const f16x8*)hh;
    int arow = rbase + l15;
    if (arow >= NN) arow = NN - 1;      // clamp; polluted C rows are store-guarded
    f16x8 a[4];
#pragma unroll
    for (int ks = 0; ks < 4; ks++)
        a[ks] = hh8[(size_t)arow * 16 + ks * 4 + q];

    const f16x8* wp8 = (const f16x8*)Wp;
#pragma unroll
    for (int nt = 0; nt < 8; nt++) {
        f32x4 acc = {0.f, 0.f, 0.f, 0.f};
#pragma unroll
        for (int ks = 0; ks < 4; ks++) {
            f16x8 bf = wp8[(ks * 8 + nt) * 64 + lane];
            acc = __builtin_amdgcn_mfma_f32_16x16x32_f16(a[ks], bf, acc, 0, 0, 0);
        }
#pragma unroll
        for (int r = 0; r < 4; r++)
            Ls[wave][q * 4 + r][nt * 16 + l15] = (_Float16)acc[r];
    }

    f16x8* m8 = (f16x8*)m;
#pragma unroll
    for (int it = 0; it < 4; it++) {
        int c = it * 64 + lane;
        int rr = c >> 4, ck = c & 15;
        int row = rbase + rr;
        if (row < NN) {
            f16x8 v = *(const f16x8*)&Ls[wave][rr][ck * 8];
            m8[(size_t)row * 16 + ck] = v;
        }
    }
}

// ---------------- fused aggregate + bias + LN + relu + residual (all-fp16 state) ----------------
// r6 evidence: k_agg is pinned at the ~3.4-3.8 TB/s random-gather fabric ceiling;
// only byte reduction helps. fp16 hh replaces fp32 h (residual) AND bf16 hb:
// -51MB fetch, -50MB write per dispatch. fp16 m halves rounding error vs bf16.

__global__ __launch_bounds__(256) void k_agg(const _Float16* __restrict__ m, _Float16* __restrict__ hh,
                                             const float* __restrict__ dis, const int* __restrict__ rp,
                                             const int* __restrict__ col, const float* __restrict__ b,
                                             const float* __restrict__ gamma, const float* __restrict__ beta) {
    int tid = threadIdx.x;
    int lane = tid & 63;
    int q = lane >> 4;      // edge slot within gather group
    int l4 = lane & 15;     // cols 8*l4 .. 8*l4+7
    int node = __builtin_amdgcn_readfirstlane(blockIdx.x * 4 + (tid >> 6));
    if (node >= NN) return;

    const f16x8* m8 = (const f16x8*)m;

    float dn = dis[node];
    float a[8];
#pragma unroll
    for (int j = 0; j < 8; j++) a[j] = 0.f;
    if (q == 0) {  // self-loop counted once
        f16x8 sv = m8[(size_t)node * 16 + l4];
        float ws = dn * dn;
#pragma unroll
        for (int j = 0; j < 8; j++) a[j] = (float)sv[j] * ws;
    }

    int e0 = rp[node], e1 = rp[node + 1];
    int e = e0 + q;
    for (; e + 12 < e1; e += 16) {
        int s0 = col[e];
        int s1 = col[e + 4];
        int s2 = col[e + 8];
        int s3 = col[e + 12];
        float w0 = dis[s0];
        float w1 = dis[s1];
        float w2 = dis[s2];
        float w3 = dis[s3];
        f16x8 v0 = m8[(size_t)s0 * 16 + l4];
        f16x8 v1 = m8[(size_t)s1 * 16 + l4];
        f16x8 v2 = m8[(size_t)s2 * 16 + l4];
        f16x8 v3 = m8[(size_t)s3 * 16 + l4];
        w0 *= dn; w1 *= dn; w2 *= dn; w3 *= dn;
#pragma unroll
        for (int j = 0; j < 8; j++) {
            a[j] += (float)v0[j] * w0;
            a[j] += (float)v1[j] * w1;
            a[j] += (float)v2[j] * w2;
            a[j] += (float)v3[j] * w3;
        }
    }
    for (; e < e1; e += 4) {
        int s = col[e];
        float w = dis[s] * dn;
        f16x8 v = m8[(size_t)s * 16 + l4];
#pragma unroll
        for (int j = 0; j < 8; j++) a[j] += (float)v[j] * w;
    }

    // combine the 4 edge-slot quarters (lanes with equal l4 hold same cols)
#pragma unroll
    for (int j = 0; j < 8; j++) {
        a[j] += __shfl_xor(a[j], 16, 64);
        a[j] += __shfl_xor(a[j], 32, 64);
    }

    float4 b0 = ((const float4*)b)[2 * l4];
    float4 b1 = ((const float4*)b)[2 * l4 + 1];
    a[0] += b0.x; a[1] += b0.y; a[2] += b0.z; a[3] += b0.w;
    a[4] += b1.x; a[5] += b1.y; a[6] += b1.z; a[7] += b1.w;

    // LayerNorm over 128 cols (reduce across the 16 l4 groups; quarters identical)
    float ssum = 0.f;
#pragma unroll
    for (int j = 0; j < 8; j++) ssum += a[j];
#pragma unroll
    for (int off = 8; off > 0; off >>= 1) ssum += __shfl_xor(ssum, off, 64);
    float mu = ssum * (1.f / 128.f);
    float d[8];
    float vsum = 0.f;
#pragma unroll
    for (int j = 0; j < 8; j++) { d[j] = a[j] - mu; vsum += d[j] * d[j]; }
#pragma unroll
    for (int off = 8; off > 0; off >>= 1) vsum += __shfl_xor(vsum, off, 64);
    float rs = rsqrtf(vsum * (1.f / 128.f) + EPS);

    if (q == 0) {
        float4 g0 = ((const float4*)gamma)[2 * l4];
        float4 g1 = ((const float4*)gamma)[2 * l4 + 1];
        float4 t0 = ((const float4*)beta)[2 * l4];
        float4 t1 = ((const float4*)beta)[2 * l4 + 1];
        f16x8 r8 = ((const f16x8*)hh)[(size_t)node * 16 + l4];
        float o[8];
        o[0] = fmaxf(d[0] * rs * g0.x + t0.x, 0.f) + (float)r8[0];
        o[1] = fmaxf(d[1] * rs * g0.y + t0.y, 0.f) + (float)r8[1];
        o[2] = fmaxf(d[2] * rs * g0.z + t0.z, 0.f) + (float)r8[2];
        o[3] = fmaxf(d[3] * rs * g0.w + t0.w, 0.f) + (float)r8[3];
        o[4] = fmaxf(d[4] * rs * g1.x + t1.x, 0.f) + (float)r8[4];
        o[5] = fmaxf(d[5] * rs * g1.y + t1.y, 0.f) + (float)r8[5];
        o[6] = fmaxf(d[6] * rs * g1.z + t1.z, 0.f) + (float)r8[6];
        o[7] = fmaxf(d[7] * rs * g1.w + t1.w, 0.f) + (float)r8[7];
        f16x8 oh;
#pragma unroll
        for (int j = 0; j < 8; j++) oh[j] = (_Float16)o[j];
        __builtin_nontemporal_store(oh, &((f16x8*)hh)[(size_t)node * 16 + l4]);
    }
}

// ---------------- pooling ----------------

__global__ void k_range(const int* __restrict__ batch, int* __restrict__ gstart, int* __restrict__ gend) {
    int n = blockIdx.x * 256 + threadIdx.x;
    if (n < NN) {
        int g = batch[n];
        atomicMin(&gstart[g], n);
        atomicMax(&gend[g], n + 1);
    }
}

__global__ __launch_bounds__(256) void k_pool(const _Float16* __restrict__ hh, const int* __restrict__ gstart,
                                              const int* __restrict__ gend, const float* __restrict__ Wout,
                                              const float* __restrict__ bout, float* __restrict__ out) {
    int tid = threadIdx.x;
    int lane = tid & 63;
    int g = blockIdx.x * 4 + (tid >> 6);
    if (g >= NG) return;

    int s = gstart[g], e = gend[g];
    const f16x2* h2 = (const f16x2*)hh;
    float axx = 0.f, ayy = 0.f;
    if (s < e) {
        for (int n = s; n < e; n++) {
            f16x2 v = h2[(size_t)n * 64 + lane];
            axx += (float)v[0];
            ayy += (float)v[1];
        }
        float inv = 1.f / (float)(e - s);
        axx *= inv;
        ayy *= inv;
    }
    float2 w = ((const float2*)Wout)[lane];
    float p = axx * w.x + ayy * w.y;
#pragma unroll
    for (int off = 32; off > 0; off >>= 1) p += __shfl_xor(p, off, 64);
    if (lane == 0) out[g] = p + bout[0];
}

// ---------------- launcher ----------------

extern "C" void kernel_launch(void* const* d_in, const int* in_sizes, int n_in,
                              void* d_out, int out_size, void* d_ws, size_t ws_size,
                              hipStream_t stream) {
    const float* x       = (const float*)d_in[0];
    const int*   edge    = (const int*)d_in[1];
    const int*   batch   = (const int*)d_in[2];
    const float* W_embed = (const float*)d_in[3];
    const float* b_embed = (const float*)d_in[4];
    const float* W_gnn   = (const float*)d_in[5];
    const float* b_gnn   = (const float*)d_in[6];
    const float* gamma   = (const float*)d_in[7];
    const float* beta    = (const float*)d_in[8];
    const float* W_out   = (const float*)d_in[9];
    const float* b_out   = (const float*)d_in[10];
    float* out = (float*)d_out;

    char* ws = (char*)d_ws;
    size_t off = 0;
    auto alloc = [&](size_t bytes) -> char* {
        char* p = ws + off;
        off += (bytes + 255) & ~(size_t)255;
        return p;
    };
    _Float16*     hh   = (_Float16*)alloc((size_t)NN * H * 2);
    _Float16*     m    = (_Float16*)alloc((size_t)NN * H * 2);
    _Float16*     Wp   = (_Float16*)alloc((size_t)NL * 4 * 8 * 512 * 2);
    float*        dis  = (float*)alloc((size_t)NN * 4);
    int*          rp   = (int*)alloc((size_t)(NN + 1) * 4);
    int*          col  = (int*)alloc((size_t)NE * 4);
    unsigned int* ebuf = (unsigned int*)alloc((size_t)NE * 4);
    int*          bcnt  = (int*)alloc((NBKT + 1) * 4);
    int*          bbase = (int*)alloc((NBKT + 1) * 4);
    int*          bfill = (int*)alloc((NBKT + 1) * 4);
    int*   gstart = (int*)alloc((size_t)NG * 4);
    int*   gend   = (int*)alloc((size_t)NG * 4);

    const int* srcp = edge;
    const int* dstp = edge + NE;

    k_init<<<(NG + 255) / 256, 256, 0, stream>>>(bcnt, bfill, gstart, gend);
    k_bhist<<<NBB, 256, 0, stream>>>(dstp, bcnt);
    k_bscan<<<1, 128, 0, stream>>>(bcnt, bbase);
    k_bscatter<<<NBB, 256, 0, stream>>>(srcp, dstp, bbase, bfill, ebuf);
    k_bcsr<<<NBKT, 256, 0, stream>>>(ebuf, bbase, rp, col, dis);

    k_wpack<<<32, 256, 0, stream>>>(W_gnn, Wp);
    k_embed<<<NN / 2, 256, 0, stream>>>(x, W_embed, b_embed, hh);

    for (int l = 0; l < NL; l++) {
        k_gemm<<<(NN + 63) / 64, 256, 0, stream>>>(hh, Wp + (size_t)l * 4 * 8 * 512, m);
        k_agg<<<(NN + 3) / 4, 256, 0, stream>>>(m, hh, dis, rp, col,
                                                b_gnn + l * H, gamma + l * H, beta + l * H);
    }

    k_range<<<(NN + 255) / 256, 256, 0, stream>>>(batch, gstart, gend);
    k_pool<<<NG / 4, 256, 0, stream>>>(hh, gstart, gend, W_out, b_out, out);
}

// Round 8
// 557.035 us; speedup vs baseline: 2.3539x; 1.0533x over previous
//
#include <hip/hip_runtime.h>

#define NN 100000
#define NE 1600000
#define DIM0 11
#define H 128
#define NL 4
#define NG 4096
#define EPS 1e-5f

#define NBKT 98        // buckets of 1024 nodes: bucket = dst >> 10
#define CAP 18432      // fixed bucket capacity (mean 16384, sigma 127 -> 16 sigma)
#define EPB 4096       // edges per block in scatter phase
static constexpr int NBB = (NE + EPB - 1) / EPB;  // 391

typedef _Float16 f16x8 __attribute__((ext_vector_type(8)));
typedef _Float16 f16x2 __attribute__((ext_vector_type(2)));
typedef float f32x4 __attribute__((ext_vector_type(4)));

// ---------------- init ----------------

__global__ void k_init(int* __restrict__ bfill, int* __restrict__ gstart, int* __restrict__ gend) {
    int i = blockIdx.x * 256 + threadIdx.x;
    if (i <= NBKT) bfill[i] = 0;
    if (i < NG) { gstart[i] = 0x7fffffff; gend[i] = 0; }
}

// ---------------- bucketed CSR build (fixed-capacity: no global scan needed) ----------------

__global__ __launch_bounds__(256) void k_bscatter(const int* __restrict__ src, const int* __restrict__ dst,
                                                  int* __restrict__ bfill, unsigned int* __restrict__ ebuf) {
    __shared__ int lc[NBKT];
    __shared__ int lbase[NBKT];
    int t = threadIdx.x;
    for (int i = t; i < NBKT; i += 256) lc[i] = 0;
    __syncthreads();
    int base = blockIdx.x * EPB;
    int rank[16];
    int bk[16];
    unsigned pk[16];
#pragma unroll
    for (int i = 0; i < 16; i++) {
        int e = base + i * 256 + t;
        if (e < NE) {
            int d = dst[e];
            int s = src[e];
            int b = d >> 10;
            bk[i] = b;
            pk[i] = (unsigned)s | ((unsigned)(d & 1023) << 17);
            rank[i] = atomicAdd(&lc[b], 1);
        } else bk[i] = -1;
    }
    __syncthreads();
    for (int i = t; i < NBKT; i += 256)
        lbase[i] = i * CAP + (lc[i] ? atomicAdd(&bfill[i], lc[i]) : 0);
    __syncthreads();
#pragma unroll
    for (int i = 0; i < 16; i++) {
        if (bk[i] >= 0)
            ebuf[lbase[bk[i]] + rank[i]] = pk[i];
    }
}

// One block per bucket: count -> dis, LDS scan -> rps/rpe, LDS-atomic scatter -> col.
__global__ __launch_bounds__(256) void k_bcsr(const unsigned int* __restrict__ ebuf,
                                              const int* __restrict__ bfill,
                                              int* __restrict__ rps, int* __restrict__ rpe,
                                              int* __restrict__ col, float* __restrict__ dis) {
    __shared__ int lcnt[1024];
    __shared__ int lfill[1024];
    __shared__ int tsc[256];
    int t = threadIdx.x;
    int b = blockIdx.x;
    int cb = b * CAP;
    int ecnt = bfill[b];
    int n0 = b << 10;
    int nb = min(1024, NN - n0);

    for (int i = t; i < 1024; i += 256) { lcnt[i] = 0; lfill[i] = 0; }
    __syncthreads();

#pragma unroll 4
    for (int i = t; i < ecnt; i += 256) {
        unsigned p = ebuf[cb + i];
        atomicAdd(&lcnt[p >> 17], 1);
    }
    __syncthreads();

    for (int n = t; n < nb; n += 256)
        dis[n0 + n] = rsqrtf((float)(lcnt[n] + 1));

    int v0 = lcnt[4 * t], v1 = lcnt[4 * t + 1], v2 = lcnt[4 * t + 2], v3 = lcnt[4 * t + 3];
    int ts = v0 + v1 + v2 + v3;
    tsc[t] = ts;
    __syncthreads();
    for (int off = 1; off < 256; off <<= 1) {
        int x = (t >= off) ? tsc[t - off] : 0;
        __syncthreads();
        tsc[t] += x;
        __syncthreads();
    }
    int ex = tsc[t] - ts;
    lcnt[4 * t] = ex;
    lcnt[4 * t + 1] = ex + v0;
    lcnt[4 * t + 2] = ex + v0 + v1;
    lcnt[4 * t + 3] = ex + v0 + v1 + v2;
    __syncthreads();

    for (int n = t; n < nb; n += 256) {
        int st = lcnt[n];
        int en = (n + 1 < 1024) ? ((n + 1 < nb) ? lcnt[n + 1] : ecnt) : ecnt;
        rps[n0 + n] = cb + st;
        rpe[n0 + n] = cb + en;
    }
    __syncthreads();

#pragma unroll 4
    for (int i = t; i < ecnt; i += 256) {
        unsigned p = ebuf[cb + i];
        int dl = p >> 17;
        int s = (int)(p & 0x1FFFFu);
        col[cb + lcnt[dl] + atomicAdd(&lfill[dl], 1)] = s;
    }
}

// ---------------- embed: hh = fp16(relu(x @ W_embed + b)) ----------------

__global__ __launch_bounds__(256) void k_embed(const float* __restrict__ x, const float* __restrict__ W,
                                               const float* __restrict__ b, _Float16* __restrict__ hh) {
    __shared__ float Ws[DIM0 * H];
    int tid = threadIdx.x;
    for (int i = tid; i < DIM0 * H; i += 256) Ws[i] = W[i];
    __syncthreads();
    int node = blockIdx.x * 2 + (tid >> 7);
    int c = tid & 127;
    if (node < NN) {
        float acc = b[c];
#pragma unroll
        for (int k = 0; k < DIM0; k++) acc += x[node * DIM0 + k] * Ws[k * H + c];
        hh[(size_t)node * H + c] = (_Float16)fmaxf(acc, 0.f);
    }
}

// ---------------- W pack: W[l][k][n] fp32 -> B-fragment-layout fp16 ----------------

__global__ __launch_bounds__(256) void k_wpack(const float* __restrict__ W, _Float16* __restrict__ Wp) {
    int t = blockIdx.x * 256 + threadIdx.x;   // 8192 threads
    int lane = t & 63;
    int idx = t >> 6;          // 0..127
    int nt = idx & 7;
    int ks = (idx >> 3) & 3;
    int l = idx >> 5;
    int q = lane >> 4, l15 = lane & 15;
    const float* Wl = W + (size_t)l * H * H;
    _Float16* o = Wp + (size_t)idx * 512 + lane * 8;
#pragma unroll
    for (int j = 0; j < 8; j++)
        o[j] = (_Float16)(Wl[(ks * 32 + q * 8 + j) * H + nt * 16 + l15]);
}

// ---------------- aggregate only: ags = segsum(norm * hh[src]) + dn^2 * hh ----------------
// r7 evidence: gather pinned at ~45G lines/s fetch floor (207MB = 8 XCD x 25.9MB
// per layer, L2 captures all intra-XCD reuse). Reordered agg-then-GEMM (linearity)
// so this kernel drops the residual read and the bias/LN/relu tail.

__global__ __launch_bounds__(256) void k_agg2(const _Float16* __restrict__ hh, _Float16* __restrict__ ags,
                                              const float* __restrict__ dis, const int* __restrict__ rps,
                                              const int* __restrict__ rpe, const int* __restrict__ col) {
    int tid = threadIdx.x;
    int lane = tid & 63;
    int q = lane >> 4;      // edge slot within gather group
    int l4 = lane & 15;     // cols 8*l4 .. 8*l4+7
    int node = __builtin_amdgcn_readfirstlane(blockIdx.x * 4 + (tid >> 6));
    if (node >= NN) return;

    const f16x8* h8 = (const f16x8*)hh;

    float dn = dis[node];
    float a[8];
#pragma unroll
    for (int j = 0; j < 8; j++) a[j] = 0.f;
    if (q == 0) {  // self-loop counted once
        f16x8 sv = h8[(size_t)node * 16 + l4];
        float ws = dn * dn;
#pragma unroll
        for (int j = 0; j < 8; j++) a[j] = (float)sv[j] * ws;
    }

    int e0 = rps[node], e1 = rpe[node];
    int e = e0 + q;
    for (; e + 12 < e1; e += 16) {
        int s0 = col[e];
        int s1 = col[e + 4];
        int s2 = col[e + 8];
        int s3 = col[e + 12];
        float w0 = dis[s0];
        float w1 = dis[s1];
        float w2 = dis[s2];
        float w3 = dis[s3];
        f16x8 v0 = h8[(size_t)s0 * 16 + l4];
        f16x8 v1 = h8[(size_t)s1 * 16 + l4];
        f16x8 v2 = h8[(size_t)s2 * 16 + l4];
        f16x8 v3 = h8[(size_t)s3 * 16 + l4];
        w0 *= dn; w1 *= dn; w2 *= dn; w3 *= dn;
#pragma unroll
        for (int j = 0; j < 8; j++) {
            a[j] += (float)v0[j] * w0;
            a[j] += (float)v1[j] * w1;
            a[j] += (float)v2[j] * w2;
            a[j] += (float)v3[j] * w3;
        }
    }
    for (; e < e1; e += 4) {
        int s = col[e];
        float w = dis[s] * dn;
        f16x8 v = h8[(size_t)s * 16 + l4];
#pragma unroll
        for (int j = 0; j < 8; j++) a[j] += (float)v[j] * w;
    }

    // combine the 4 edge-slot quarters
#pragma unroll
    for (int j = 0; j < 8; j++) {
        a[j] += __shfl_xor(a[j], 16, 64);
        a[j] += __shfl_xor(a[j], 32, 64);
    }

    if (q == 0) {
        f16x8 o;
#pragma unroll
        for (int j = 0; j < 8; j++) o[j] = (_Float16)a[j];
        ((f16x8*)ags)[(size_t)node * 16 + l4] = o;
    }
}

// ---------------- fused GEMM + bias + LN + relu + residual ----------------
// hh_new = relu(LN(ags @ W + b)) + hh_old. Wave computes 16x128; LN row stats
// via shfl_xor within the 16-lane C-layout groups (row = q*4+reg, col = lane&15).

__global__ __launch_bounds__(256) void k_gemmf(const _Float16* __restrict__ ags,
                                               const _Float16* __restrict__ Wp,
                                               const float* __restrict__ bias,
                                               const float* __restrict__ gamma,
                                               const float* __restrict__ beta,
                                               _Float16* __restrict__ hh) {
    __shared__ _Float16 Ls[4][16][136];  // row stride 272B, bank-spread
    int tid = threadIdx.x;
    int wave = tid >> 6;
    int lane = tid & 63;
    int q = lane >> 4, l15 = lane & 15;
    int rbase = blockIdx.x * 64 + wave * 16;

    const f16x8* ag8 = (const f16x8*)ags;
    int arow = rbase + l15;
    if (arow >= NN) arow = NN - 1;      // clamp; polluted rows are store-guarded
    f16x8 a[4];
#pragma unroll
    for (int ks = 0; ks < 4; ks++)
        a[ks] = ag8[(size_t)arow * 16 + ks * 4 + q];

    float bb[8], gm[8], bt[8];
#pragma unroll
    for (int nt = 0; nt < 8; nt++) {
        bb[nt] = bias[nt * 16 + l15];
        gm[nt] = gamma[nt * 16 + l15];
        bt[nt] = beta[nt * 16 + l15];
    }

    const f16x8* wp8 = (const f16x8*)Wp;
    f32x4 acc[8];
#pragma unroll
    for (int nt = 0; nt < 8; nt++) {
        acc[nt] = (f32x4){0.f, 0.f, 0.f, 0.f};
#pragma unroll
        for (int ks = 0; ks < 4; ks++) {
            f16x8 bf = wp8[(ks * 8 + nt) * 64 + lane];
            acc[nt] = __builtin_amdgcn_mfma_f32_16x16x32_f16(a[ks], bf, acc[nt], 0, 0, 0);
        }
#pragma unroll
        for (int r = 0; r < 4; r++) acc[nt][r] += bb[nt];
    }

    // LN row stats: rows q*4+r, cols spread over 16 lanes (same q) x 8 nt
    float mu[4], rs[4];
#pragma unroll
    for (int r = 0; r < 4; r++) {
        float s = 0.f;
#pragma unroll
        for (int nt = 0; nt < 8; nt++) s += acc[nt][r];
#pragma unroll
        for (int off = 8; off > 0; off >>= 1) s += __shfl_xor(s, off, 64);
        mu[r] = s * (1.f / 128.f);
    }
#pragma unroll
    for (int r = 0; r < 4; r++) {
        float v = 0.f;
#pragma unroll
        for (int nt = 0; nt < 8; nt++) {
            float d = acc[nt][r] - mu[r];
            v += d * d;
        }
#pragma unroll
        for (int off = 8; off > 0; off >>= 1) v += __shfl_xor(v, off, 64);
        rs[r] = rsqrtf(v * (1.f / 128.f) + EPS);
    }

#pragma unroll
    for (int nt = 0; nt < 8; nt++)
#pragma unroll
        for (int r = 0; r < 4; r++) {
            float o = fmaxf((acc[nt][r] - mu[r]) * rs[r] * gm[nt] + bt[nt], 0.f);
            Ls[wave][q * 4 + r][nt * 16 + l15] = (_Float16)o;
        }

    // epilogue: coalesced read from LDS + residual add + store (wave-private region)
    f16x8* hh8 = (f16x8*)hh;
#pragma unroll
    for (int it = 0; it < 4; it++) {
        int c = it * 64 + lane;
        int rr = c >> 4, ck = c & 15;
        int row = rbase + rr;
        if (row < NN) {
            f16x8 ln = *(const f16x8*)&Ls[wave][rr][ck * 8];
            f16x8 res = hh8[(size_t)row * 16 + ck];
            f16x8 o;
#pragma unroll
            for (int j = 0; j < 8; j++) o[j] = (_Float16)((float)ln[j] + (float)res[j]);
            hh8[(size_t)row * 16 + ck] = o;
        }
    }
}

// ---------------- pooling ----------------

__global__ void k_range(const int* __restrict__ batch, int* __restrict__ gstart, int* __restrict__ gend) {
    int n = blockIdx.x * 256 + threadIdx.x;
    if (n < NN) {
        int g = batch[n];
        atomicMin(&gstart[g], n);
        atomicMax(&gend[g], n + 1);
    }
}

__global__ __launch_bounds__(256) void k_pool(const _Float16* __restrict__ hh, const int* __restrict__ gstart,
                                              const int* __restrict__ gend, const float* __restrict__ Wout,
                                              const float* __restrict__ bout, float* __restrict__ out) {
    int tid = threadIdx.x;
    int lane = tid & 63;
    int g = blockIdx.x * 4 + (tid >> 6);
    if (g >= NG) return;

    int s = gstart[g], e = gend[g];
    const f16x2* h2 = (const f16x2*)hh;
    float axx = 0.f, ayy = 0.f;
    if (s < e) {
        for (int n = s; n < e; n++) {
            f16x2 v = h2[(size_t)n * 64 + lane];
            axx += (float)v[0];
            ayy += (float)v[1];
        }
        float inv = 1.f / (float)(e - s);
        axx *= inv;
        ayy *= inv;
    }
    float2 w = ((const float2*)Wout)[lane];
    float p = axx * w.x + ayy * w.y;
#pragma unroll
    for (int off = 32; off > 0; off >>= 1) p += __shfl_xor(p, off, 64);
    if (lane == 0) out[g] = p + bout[0];
}

// ---------------- launcher ----------------

extern "C" void kernel_launch(void* const* d_in, const int* in_sizes, int n_in,
                              void* d_out, int out_size, void* d_ws, size_t ws_size,
                              hipStream_t stream) {
    const float* x       = (const float*)d_in[0];
    const int*   edge    = (const int*)d_in[1];
    const int*   batch   = (const int*)d_in[2];
    const float* W_embed = (const float*)d_in[3];
    const float* b_embed = (const float*)d_in[4];
    const float* W_gnn   = (const float*)d_in[5];
    const float* b_gnn   = (const float*)d_in[6];
    const float* gamma   = (const float*)d_in[7];
    const float* beta    = (const float*)d_in[8];
    const float* W_out   = (const float*)d_in[9];
    const float* b_out   = (const float*)d_in[10];
    float* out = (float*)d_out;

    char* ws = (char*)d_ws;
    size_t off = 0;
    auto alloc = [&](size_t bytes) -> char* {
        char* p = ws + off;
        off += (bytes + 255) & ~(size_t)255;
        return p;
    };
    _Float16*     hh   = (_Float16*)alloc((size_t)NN * H * 2);
    _Float16*     ags  = (_Float16*)alloc((size_t)NN * H * 2);
    _Float16*     Wp   = (_Float16*)alloc((size_t)NL * 4 * 8 * 512 * 2);
    float*        dis  = (float*)alloc((size_t)NN * 4);
    int*          rps  = (int*)alloc((size_t)NN * 4);
    int*          rpe  = (int*)alloc((size_t)NN * 4);
    int*          col  = (int*)alloc((size_t)NBKT * CAP * 4);
    unsigned int* ebuf = (unsigned int*)alloc((size_t)NBKT * CAP * 4);
    int*          bfill = (int*)alloc((NBKT + 1) * 4);
    int*   gstart = (int*)alloc((size_t)NG * 4);
    int*   gend   = (int*)alloc((size_t)NG * 4);

    const int* srcp = edge;
    const int* dstp = edge + NE;

    k_init<<<(NG + 255) / 256, 256, 0, stream>>>(bfill, gstart, gend);
    k_bscatter<<<NBB, 256, 0, stream>>>(srcp, dstp, bfill, ebuf);
    k_bcsr<<<NBKT, 256, 0, stream>>>(ebuf, bfill, rps, rpe, col, dis);

    k_wpack<<<32, 256, 0, stream>>>(W_gnn, Wp);
    k_embed<<<NN / 2, 256, 0, stream>>>(x, W_embed, b_embed, hh);

    for (int l = 0; l < NL; l++) {
        k_agg2<<<(NN + 3) / 4, 256, 0, stream>>>(hh, ags, dis, rps, rpe, col);
        k_gemmf<<<(NN + 63) / 64, 256, 0, stream>>>(ags, Wp + (size_t)l * 4 * 8 * 512,
                                                    b_gnn + l * H, gamma + l * H, beta + l * H, hh);
    }

    k_range<<<(NN + 255) / 256, 256, 0, stream>>>(batch, gstart, gend);
    k_pool<<<NG / 4, 256, 0, stream>>>(hh, gstart, gend, W_out, b_out, out);
}